// Round 1
// baseline (437.402 us; speedup 1.0000x reference)
//
#include <hip/hip_runtime.h>

#define HD      64
#define VOC     64
#define HALF    32
#define BATCH   128
#define SEQLEN  2048

// ---------------------------------------------------------------------------
// Kernel 1: build per-vocab table.
// The whole per-token pipeline (embed -> MLP -> LN -> Ws/We proj) depends only
// on the vocab id (VOCAB_SIZE=64). One block per vocab id, 64 threads (1 wave).
// Outputs: Ktab[2][64][32] (sem, epi), rden[2][64] = 1/(||k||^2 + 1e-6).
// ---------------------------------------------------------------------------
__global__ __launch_bounds__(64) void build_table_kernel(
    const float* __restrict__ embed, const float* __restrict__ W1, const float* __restrict__ b1,
    const float* __restrict__ W2,    const float* __restrict__ b2,
    const float* __restrict__ ln_g,  const float* __restrict__ ln_b,
    const float* __restrict__ Ws,    const float* __restrict__ bs,
    const float* __restrict__ We,    const float* __restrict__ be,
    float* __restrict__ Ktab, float* __restrict__ rden)
{
    const int v = blockIdx.x;
    const int j = threadIdx.x;       // 0..63

    __shared__ float e_s[64];
    __shared__ float u_s[128];
    __shared__ float h_s[64];

    float e = embed[v*HD + j];
    e_s[j] = e;
    __syncthreads();

    // u = relu(e @ W1 + b1): thread j computes u[j], u[j+64]
    float u0 = b1[j], u1 = b1[j + 64];
    #pragma unroll
    for (int i = 0; i < 64; ++i) {
        float ei = e_s[i];
        u0 = fmaf(ei, W1[i*128 + j],      u0);
        u1 = fmaf(ei, W1[i*128 + 64 + j], u1);
    }
    u_s[j]      = fmaxf(u0, 0.f);
    u_s[j + 64] = fmaxf(u1, 0.f);
    __syncthreads();

    // ff = u @ W2 + b2
    float ff = b2[j];
    #pragma unroll
    for (int c = 0; c < 128; ++c) ff = fmaf(u_s[c], W2[c*64 + j], ff);

    // layernorm(e + ff)
    float x = e + ff;
    float mu = x;
    #pragma unroll
    for (int m = 32; m; m >>= 1) mu += __shfl_xor(mu, m, 64);
    mu *= (1.f / 64.f);
    float d = x - mu;
    float var = d * d;
    #pragma unroll
    for (int m = 32; m; m >>= 1) var += __shfl_xor(var, m, 64);
    var *= (1.f / 64.f);
    float h = d * rsqrtf(var + 1e-5f) * ln_g[j] + ln_b[j];
    h_s[j] = h;
    __syncthreads();

    // projections: lanes 0..31 -> k_sem, lanes 32..63 -> k_epi
    const int mm = j >> 5;
    const int jj = j & 31;
    const float* W  = mm ? We : Ws;
    float acc = mm ? be[jj] : bs[jj];
    #pragma unroll
    for (int i = 0; i < 64; ++i) acc = fmaf(h_s[i], W[i*32 + jj], acc);
    Ktab[(mm*VOC + v)*HALF + jj] = acc;

    // 1/(||k||^2 + 1e-6), reduced within each 32-lane half
    float s = acc * acc;
    #pragma unroll
    for (int m = 16; m; m >>= 1) s += __shfl_xor(s, m, 32);
    if (jj == 0) rden[mm*VOC + v] = 1.f / (s + 1e-6f);
}

// ---------------------------------------------------------------------------
// Kernel 2: the sequential scan. One wave per (batch, matrix): 256 blocks.
// Rows are independent; lane l owns row (l&31), column half (l>>5)*16.
// State M[i, 16 cols] lives in 16 VGPRs. k comes from the LDS vocab table.
// ---------------------------------------------------------------------------
__global__ __launch_bounds__(64) void scan_kernel(
    const int*   __restrict__ seq,
    const float* __restrict__ Ktab,
    const float* __restrict__ rden,
    float*       __restrict__ ctx)
{
    const int bm = blockIdx.x;     // 0..255
    const int b  = bm >> 1;
    const int mm = bm & 1;         // 0 = sem, 1 = epi
    const int l  = threadIdx.x;
    const int i  = l & 31;         // row
    const int hh = l >> 5;         // column half

    __shared__ float kt[VOC * HALF];   // 8 KB: this matrix's k-table
    __shared__ float rd_s[VOC];
    __shared__ int   sq[SEQLEN];       // 8 KB: this batch's token ids

    for (int idx = l; idx < VOC * HALF; idx += 64) kt[idx] = Ktab[mm*VOC*HALF + idx];
    if (l < VOC) rd_s[l] = rden[mm*VOC + l];
    const int* seqb = seq + b * SEQLEN;
    for (int idx = l; idx < SEQLEN; idx += 64) sq[idx] = seqb[idx];
    __syncthreads();

    float m[16];
    #pragma unroll
    for (int c = 0; c < 16; ++c) m[c] = 0.f;

    const float wstep = 1.0f / (float)SEQLEN;

    for (int t = 0; t < SEQLEN - 1; ++t) {
        const int v = sq[t];
        const float* kvp = &kt[v*HALF + hh*16];
        float kv[16];
        #pragma unroll
        for (int c = 0; c < 16; c += 4) {
            float4 f = *reinterpret_cast<const float4*>(kvp + c);
            kv[c] = f.x; kv[c+1] = f.y; kv[c+2] = f.z; kv[c+3] = f.w;
        }
        const float ki = kt[v*HALF + i];
        const float rd = rd_s[v];

        // dot(M[i, half], k[half]) as 4 parallel FMA chains + tree
        float p0 = 0.f, p1 = 0.f, p2 = 0.f, p3 = 0.f;
        #pragma unroll
        for (int c = 0; c < 16; c += 4) {
            p0 = fmaf(m[c],   kv[c],   p0);
            p1 = fmaf(m[c+1], kv[c+1], p1);
            p2 = fmaf(m[c+2], kv[c+2], p2);
            p3 = fmaf(m[c+3], kv[c+3], p3);
        }
        float p = (p0 + p1) + (p2 + p3);
        p += __shfl_xor(p, 32, 64);           // combine the two column halves

        const float w    = mm ? (float)(t + 1) * wstep : 1.0f;
        const float coef = (ki - p * rd) * w;
        #pragma unroll
        for (int c = 0; c < 16; ++c) m[c] = fmaf(coef, kv[c], m[c]);
    }

    // query: q projections are the table entries of the last token
    {
        const int v = sq[SEQLEN - 1];
        const float* kvp = &kt[v*HALF + hh*16];
        float p0 = 0.f, p1 = 0.f, p2 = 0.f, p3 = 0.f;
        #pragma unroll
        for (int c = 0; c < 16; c += 4) {
            p0 = fmaf(m[c],   kvp[c],   p0);
            p1 = fmaf(m[c+1], kvp[c+1], p1);
            p2 = fmaf(m[c+2], kvp[c+2], p2);
            p3 = fmaf(m[c+3], kvp[c+3], p3);
        }
        float p = (p0 + p1) + (p2 + p3);
        p += __shfl_xor(p, 32, 64);
        if (hh == 0) ctx[b*64 + mm*32 + i] = p;
    }
}

// ---------------------------------------------------------------------------
// Kernel 3: out = ctx @ Wo + bo.  128 blocks x 64 threads.
// ---------------------------------------------------------------------------
__global__ __launch_bounds__(64) void out_kernel(
    const float* __restrict__ ctx, const float* __restrict__ Wo,
    const float* __restrict__ bo,  float* __restrict__ out)
{
    const int b = blockIdx.x;
    const int o = threadIdx.x;
    float acc = bo[o];
    #pragma unroll
    for (int i = 0; i < 64; ++i) acc = fmaf(ctx[b*64 + i], Wo[i*64 + o], acc);
    out[b*64 + o] = acc;
}

extern "C" void kernel_launch(void* const* d_in, const int* in_sizes, int n_in,
                              void* d_out, int out_size, void* d_ws, size_t ws_size,
                              hipStream_t stream)
{
    const int*   seq   = (const int*)  d_in[0];
    const float* embed = (const float*)d_in[1];
    const float* W1    = (const float*)d_in[2];
    const float* b1    = (const float*)d_in[3];
    const float* W2    = (const float*)d_in[4];
    const float* b2    = (const float*)d_in[5];
    const float* ln_g  = (const float*)d_in[6];
    const float* ln_b  = (const float*)d_in[7];
    const float* Ws    = (const float*)d_in[8];
    const float* bs    = (const float*)d_in[9];
    const float* We    = (const float*)d_in[10];
    const float* be    = (const float*)d_in[11];
    const float* Wo    = (const float*)d_in[12];
    const float* bo    = (const float*)d_in[13];
    float* out = (float*)d_out;

    float* Ktab = (float*)d_ws;                 // 2*64*32 floats
    float* rden = Ktab + 2*VOC*HALF;            // 2*64 floats
    float* ctx  = rden + 2*VOC;                 // 128*64 floats

    build_table_kernel<<<VOC, 64, 0, stream>>>(embed, W1, b1, W2, b2, ln_g, ln_b,
                                               Ws, bs, We, be, Ktab, rden);
    scan_kernel<<<BATCH*2, 64, 0, stream>>>(seq, Ktab, rden, ctx);
    out_kernel<<<BATCH, 64, 0, stream>>>(ctx, Wo, bo, out);
}

// Round 2
// 263.360 us; speedup vs baseline: 1.6609x; 1.6609x over previous
//
#include <hip/hip_runtime.h>

#define HD      64
#define VOC     64
#define HALF    32
#define BATCH   128
#define SEQLEN  2048

// ---------------------------------------------------------------------------
// Kernel 1: build per-vocab table (unchanged from R1; verified correct).
// ---------------------------------------------------------------------------
__global__ __launch_bounds__(64) void build_table_kernel(
    const float* __restrict__ embed, const float* __restrict__ W1, const float* __restrict__ b1,
    const float* __restrict__ W2,    const float* __restrict__ b2,
    const float* __restrict__ ln_g,  const float* __restrict__ ln_b,
    const float* __restrict__ Ws,    const float* __restrict__ bs,
    const float* __restrict__ We,    const float* __restrict__ be,
    float* __restrict__ Ktab, float* __restrict__ rden)
{
    const int v = blockIdx.x;
    const int j = threadIdx.x;

    __shared__ float e_s[64];
    __shared__ float u_s[128];
    __shared__ float h_s[64];

    float e = embed[v*HD + j];
    e_s[j] = e;
    __syncthreads();

    float u0 = b1[j], u1 = b1[j + 64];
    #pragma unroll
    for (int i = 0; i < 64; ++i) {
        float ei = e_s[i];
        u0 = fmaf(ei, W1[i*128 + j],      u0);
        u1 = fmaf(ei, W1[i*128 + 64 + j], u1);
    }
    u_s[j]      = fmaxf(u0, 0.f);
    u_s[j + 64] = fmaxf(u1, 0.f);
    __syncthreads();

    float ff = b2[j];
    #pragma unroll
    for (int c = 0; c < 128; ++c) ff = fmaf(u_s[c], W2[c*64 + j], ff);

    float x = e + ff;
    float mu = x;
    #pragma unroll
    for (int m = 32; m; m >>= 1) mu += __shfl_xor(mu, m, 64);
    mu *= (1.f / 64.f);
    float d = x - mu;
    float var = d * d;
    #pragma unroll
    for (int m = 32; m; m >>= 1) var += __shfl_xor(var, m, 64);
    var *= (1.f / 64.f);
    float h = d * rsqrtf(var + 1e-5f) * ln_g[j] + ln_b[j];
    h_s[j] = h;
    __syncthreads();

    const int mm = j >> 5;
    const int jj = j & 31;
    const float* W  = mm ? We : Ws;
    float acc = mm ? be[jj] : bs[jj];
    #pragma unroll
    for (int i = 0; i < 64; ++i) acc = fmaf(h_s[i], W[i*32 + jj], acc);
    Ktab[(mm*VOC + v)*HALF + jj] = acc;

    float s = acc * acc;
    #pragma unroll
    for (int m = 16; m; m >>= 1) s += __shfl_xor(s, m, 32);
    if (jj == 0) rden[mm*VOC + v] = 1.f / (s + 1e-6f);
}

// ---------------------------------------------------------------------------
// Kernel 1b: gram table G[mm][v1][v2] = k_{v1} . k_{v2}  (64x64 per matrix)
// ---------------------------------------------------------------------------
__global__ __launch_bounds__(64) void gram_kernel(
    const float* __restrict__ Ktab, float* __restrict__ Gtab)
{
    const int mm = blockIdx.x;
    const int j  = threadIdx.x;              // v2
    __shared__ float kt[VOC * HALF];
    for (int idx = j; idx < VOC * HALF; idx += 64) kt[idx] = Ktab[mm*VOC*HALF + idx];
    __syncthreads();
    for (int v1 = 0; v1 < VOC; ++v1) {
        float s0 = 0.f, s1 = 0.f;
        #pragma unroll
        for (int c = 0; c < 32; c += 2) {
            s0 = fmaf(kt[v1*HALF + c],     kt[j*HALF + c],     s0);
            s1 = fmaf(kt[v1*HALF + c + 1], kt[j*HALF + c + 1], s1);
        }
        Gtab[(mm*VOC + v1)*VOC + j] = s0 + s1;
    }
}

// ---------------------------------------------------------------------------
// Kernel 2: the scan. One wave per (batch, matrix): 256 blocks.
// Lane l: row i = l&31, column half hh = l>>5 (16 cols).
//
// Exact regrouping: p_t = m_{t-1}.k_t = (m_{t-2}.k_t) + coef_{t-1}*G[v_{t-1},v_t]
// Body t computes the NEXT step's stale dot (against pre-update m) so the
// critical recurrence is only: p = fma(coefP, gP, dstP); coef = fma(-p,rdw,kiw).
// All LDS traffic (k banks, ki, rd, G, sq) is prefetched >= 1 body ahead.
// ---------------------------------------------------------------------------
__global__ __launch_bounds__(64) void scan_kernel(
    const int*   __restrict__ seq,
    const float* __restrict__ Ktab,
    const float* __restrict__ rden,
    const float* __restrict__ Gtab,
    float*       __restrict__ ctx)
{
    const int bm = blockIdx.x;     // 0..255
    const int b  = bm >> 1;
    const int mm = bm & 1;         // 0 = sem, 1 = epi
    const int l  = threadIdx.x;
    const int i  = l & 31;         // row
    const int hh16 = (l >> 5) << 4; // column-half offset (0 or 16)

    __shared__ float kt[VOC * HALF];       // 8 KB
    __shared__ float Gs[VOC * VOC];        // 16 KB
    __shared__ float rds[VOC];             // 256 B
    __shared__ int   sq[SEQLEN];           // 8 KB

    // stage tables (vectorized)
    {
        const float4* Ksrc = (const float4*)(Ktab + mm*VOC*HALF);
        float4* Kdst = (float4*)kt;
        for (int idx = l; idx < VOC*HALF/4; idx += 64) Kdst[idx] = Ksrc[idx];
        const float4* Gsrc = (const float4*)(Gtab + mm*VOC*VOC);
        float4* Gdst = (float4*)Gs;
        for (int idx = l; idx < VOC*VOC/4; idx += 64) Gdst[idx] = Gsrc[idx];
        if (l < VOC) rds[l] = rden[mm*VOC + l];
        const int4* Ssrc = (const int4*)(seq + b*SEQLEN);
        int4* Sdst = (int4*)sq;
        for (int idx = l; idx < SEQLEN/4; idx += 64) Sdst[idx] = Ssrc[idx];
    }
    __syncthreads();

    float m[16];
    #pragma unroll
    for (int c = 0; c < 16; ++c) m[c] = 0.f;

    float kb0[16], kb1[16], kb2[16];

    const float dw = mm ? (1.0f / (float)SEQLEN) : 0.0f;
    float w = mm ? (1.0f / (float)SEQLEN) : 1.0f;   // w_0

    // token-id window
    int va = sq[0], vb = sq[1], vc = sq[2];

    // preload banks: kb0 = k_{t=0}, kb1 = k_{t=1}
    {
        const float4* kp = (const float4*)(kt + va*HALF + hh16);
        float4 f0 = kp[0], f1 = kp[1], f2 = kp[2], f3 = kp[3];
        kb0[0]=f0.x; kb0[1]=f0.y; kb0[2]=f0.z; kb0[3]=f0.w;
        kb0[4]=f1.x; kb0[5]=f1.y; kb0[6]=f1.z; kb0[7]=f1.w;
        kb0[8]=f2.x; kb0[9]=f2.y; kb0[10]=f2.z; kb0[11]=f2.w;
        kb0[12]=f3.x; kb0[13]=f3.y; kb0[14]=f3.z; kb0[15]=f3.w;
        const float4* kq = (const float4*)(kt + vb*HALF + hh16);
        float4 g0 = kq[0], g1 = kq[1], g2 = kq[2], g3 = kq[3];
        kb1[0]=g0.x; kb1[1]=g0.y; kb1[2]=g0.z; kb1[3]=g0.w;
        kb1[4]=g1.x; kb1[5]=g1.y; kb1[6]=g1.z; kb1[7]=g1.w;
        kb1[8]=g2.x; kb1[9]=g2.y; kb1[10]=g2.z; kb1[11]=g2.w;
        kb1[12]=g3.x; kb1[13]=g3.y; kb1[14]=g3.z; kb1[15]=g3.w;
    }

    // pipeline registers
    float coefP = 0.f, gP = 0.f, dstP = 0.f;
    float kiw = kt[va*HALF + i] * w;
    float rdw = rds[va] * w;

    int t = 0;

// BD = dot bank (k_{t+1}), BU = update bank (k_t), BL = load target (k_{t+2})
#define SCAN_BODY(BD, BU, BL)                                                  \
    do {                                                                       \
        /* critical recurrence (2 fma) */                                      \
        float p    = fmaf(coefP, gP, dstP);                                    \
        float coef = fmaf(-p, rdw, kiw);                                       \
        /* sq prefetch (t+3) */                                                \
        int tn = t + 3; tn = (tn < SEQLEN) ? tn : (SEQLEN - 1);                \
        int vnew = sq[tn];                                                     \
        /* stale dot: m (pre-update) . k_{t+1}, 2 chains */                    \
        float a0 = 0.f, a1 = 0.f;                                              \
        _Pragma("unroll")                                                      \
        for (int c = 0; c < 16; c += 2) {                                      \
            a0 = fmaf(m[c],   BD[c],   a0);                                    \
            a1 = fmaf(m[c+1], BD[c+1], a1);                                    \
        }                                                                      \
        float aa = a0 + a1;                                                    \
        float ao = __shfl_xor(aa, 32);                                         \
        /* prefetch loads for later bodies */                                  \
        {                                                                      \
            const float4* kp = (const float4*)(kt + vc*HALF + hh16);           \
            float4 f0 = kp[0], f1 = kp[1], f2 = kp[2], f3 = kp[3];             \
            BL[0]=f0.x; BL[1]=f0.y; BL[2]=f0.z; BL[3]=f0.w;                    \
            BL[4]=f1.x; BL[5]=f1.y; BL[6]=f1.z; BL[7]=f1.w;                    \
            BL[8]=f2.x; BL[9]=f2.y; BL[10]=f2.z; BL[11]=f2.w;                  \
            BL[12]=f3.x; BL[13]=f3.y; BL[14]=f3.z; BL[15]=f3.w;                \
        }                                                                      \
        float kiN = kt[vb*HALF + i];                                           \
        float rdN = rds[vb];                                                   \
        float gN  = Gs[va*VOC + vb];                                           \
        /* state update with k_t */                                            \
        _Pragma("unroll")                                                      \
        for (int c = 0; c < 16; ++c) m[c] = fmaf(coef, BU[c], m[c]);           \
        /* finish stale dot */                                                 \
        float dst = aa + ao;                                                   \
        /* next-step scalars */                                                \
        float wN = w + dw;                                                     \
        coefP = coef; gP = gN; dstP = dst;                                     \
        kiw = kiN * wN; rdw = rdN * wN; w = wN;                                \
        va = vb; vb = vc; vc = vnew;                                           \
        ++t;                                                                   \
    } while (0)

    // 2047 bodies = 682*3 + 1
    for (int it = 0; it < 682; ++it) {
        SCAN_BODY(kb1, kb0, kb2);
        SCAN_BODY(kb2, kb1, kb0);
        SCAN_BODY(kb0, kb2, kb1);
    }
    SCAN_BODY(kb1, kb0, kb2);   // t = 2046; its dot bank holds k_{2047} = query k
#undef SCAN_BODY

    // query: p_q = m_2046 . k_q = dstP + coefP * G[v_2046, v_q]
    float pq = fmaf(coefP, gP, dstP);
    if (hh16 == 0) ctx[b*64 + mm*32 + i] = pq;
}

// ---------------------------------------------------------------------------
// Kernel 3: out = ctx @ Wo + bo.
// ---------------------------------------------------------------------------
__global__ __launch_bounds__(64) void out_kernel(
    const float* __restrict__ ctx, const float* __restrict__ Wo,
    const float* __restrict__ bo,  float* __restrict__ out)
{
    const int b = blockIdx.x;
    const int o = threadIdx.x;
    float acc = bo[o];
    #pragma unroll
    for (int i = 0; i < 64; ++i) acc = fmaf(ctx[b*64 + i], Wo[i*64 + o], acc);
    out[b*64 + o] = acc;
}

extern "C" void kernel_launch(void* const* d_in, const int* in_sizes, int n_in,
                              void* d_out, int out_size, void* d_ws, size_t ws_size,
                              hipStream_t stream)
{
    const int*   seq   = (const int*)  d_in[0];
    const float* embed = (const float*)d_in[1];
    const float* W1    = (const float*)d_in[2];
    const float* b1    = (const float*)d_in[3];
    const float* W2    = (const float*)d_in[4];
    const float* b2    = (const float*)d_in[5];
    const float* ln_g  = (const float*)d_in[6];
    const float* ln_b  = (const float*)d_in[7];
    const float* Ws    = (const float*)d_in[8];
    const float* bs    = (const float*)d_in[9];
    const float* We    = (const float*)d_in[10];
    const float* be    = (const float*)d_in[11];
    const float* Wo    = (const float*)d_in[12];
    const float* bo    = (const float*)d_in[13];
    float* out = (float*)d_out;

    float* Ktab = (float*)d_ws;                 // 2*64*32
    float* rden = Ktab + 2*VOC*HALF;            // 2*64
    float* ctx  = rden + 2*VOC;                 // 128*64
    float* Gtab = ctx  + BATCH*64;              // 2*64*64

    build_table_kernel<<<VOC, 64, 0, stream>>>(embed, W1, b1, W2, b2, ln_g, ln_b,
                                               Ws, bs, We, be, Ktab, rden);
    gram_kernel<<<2, 64, 0, stream>>>(Ktab, Gtab);
    scan_kernel<<<BATCH*2, 64, 0, stream>>>(seq, Ktab, rden, Gtab, ctx);
    out_kernel<<<BATCH, 64, 0, stream>>>(ctx, Wo, bo, out);
}

// Round 3
// 260.089 us; speedup vs baseline: 1.6817x; 1.0126x over previous
//
#include <hip/hip_runtime.h>

#define HD      64
#define VOC     64
#define HALF    32
#define BATCH   128
#define SEQLEN  2048

// ---------------------------------------------------------------------------
// Kernel 1: build per-vocab table (unchanged; verified R1/R2).
// ---------------------------------------------------------------------------
__global__ __launch_bounds__(64) void build_table_kernel(
    const float* __restrict__ embed, const float* __restrict__ W1, const float* __restrict__ b1,
    const float* __restrict__ W2,    const float* __restrict__ b2,
    const float* __restrict__ ln_g,  const float* __restrict__ ln_b,
    const float* __restrict__ Ws,    const float* __restrict__ bs,
    const float* __restrict__ We,    const float* __restrict__ be,
    float* __restrict__ Ktab, float* __restrict__ rden)
{
    const int v = blockIdx.x;
    const int j = threadIdx.x;

    __shared__ float e_s[64];
    __shared__ float u_s[128];
    __shared__ float h_s[64];

    float e = embed[v*HD + j];
    e_s[j] = e;
    __syncthreads();

    float u0 = b1[j], u1 = b1[j + 64];
    #pragma unroll
    for (int i = 0; i < 64; ++i) {
        float ei = e_s[i];
        u0 = fmaf(ei, W1[i*128 + j],      u0);
        u1 = fmaf(ei, W1[i*128 + 64 + j], u1);
    }
    u_s[j]      = fmaxf(u0, 0.f);
    u_s[j + 64] = fmaxf(u1, 0.f);
    __syncthreads();

    float ff = b2[j];
    #pragma unroll
    for (int c = 0; c < 128; ++c) ff = fmaf(u_s[c], W2[c*64 + j], ff);

    float x = e + ff;
    float mu = x;
    #pragma unroll
    for (int m = 32; m; m >>= 1) mu += __shfl_xor(mu, m, 64);
    mu *= (1.f / 64.f);
    float d = x - mu;
    float var = d * d;
    #pragma unroll
    for (int m = 32; m; m >>= 1) var += __shfl_xor(var, m, 64);
    var *= (1.f / 64.f);
    float h = d * rsqrtf(var + 1e-5f) * ln_g[j] + ln_b[j];
    h_s[j] = h;
    __syncthreads();

    const int mm = j >> 5;
    const int jj = j & 31;
    const float* W  = mm ? We : Ws;
    float acc = mm ? be[jj] : bs[jj];
    #pragma unroll
    for (int i = 0; i < 64; ++i) acc = fmaf(h_s[i], W[i*32 + jj], acc);
    Ktab[(mm*VOC + v)*HALF + jj] = acc;

    float s = acc * acc;
    #pragma unroll
    for (int m = 16; m; m >>= 1) s += __shfl_xor(s, m, 32);
    if (jj == 0) rden[mm*VOC + v] = 1.f / (s + 1e-6f);
}

// ---------------------------------------------------------------------------
// Kernel 1b: gram table G[mm][v1][v2] = k_{v1} . k_{v2}
// ---------------------------------------------------------------------------
__global__ __launch_bounds__(64) void gram_kernel(
    const float* __restrict__ Ktab, float* __restrict__ Gtab)
{
    const int mm = blockIdx.x;
    const int j  = threadIdx.x;
    __shared__ float kt[VOC * HALF];
    for (int idx = j; idx < VOC * HALF; idx += 64) kt[idx] = Ktab[mm*VOC*HALF + idx];
    __syncthreads();
    for (int v1 = 0; v1 < VOC; ++v1) {
        float s0 = 0.f, s1 = 0.f;
        #pragma unroll
        for (int c = 0; c < 32; c += 2) {
            s0 = fmaf(kt[v1*HALF + c],     kt[j*HALF + c],     s0);
            s1 = fmaf(kt[v1*HALF + c + 1], kt[j*HALF + c + 1], s1);
        }
        Gtab[(mm*VOC + v1)*VOC + j] = s0 + s1;
    }
}

// ---------------------------------------------------------------------------
// Kernel 2: the scan. One 256-thread block per (batch, matrix) pair:
// 4 waves x (8 rows/wave, 8 lanes/row, 4 cols/lane). All 4 SIMDs of a CU busy.
//
// Distance-3 exact regrouping:
//   p_{t} = m_{t-4}.k_t + coef_{t-3} G[v_{t-3},v_t] + coef_{t-2} G[...] + coef_{t-1} G[...]
// Body t computes the raw dot D_t = m_{t-1}.k_{t+3}; its 3-shfl reduce has
// ~2 bodies of slack. 6-bank k rotation gives every ds_read >= 2 bodies slack.
// Critical recurrence stays 2 FMA: p = fma(coefP,gcur,P1); coef = fma(-p,rdw,kiw).
// ---------------------------------------------------------------------------
__global__ __launch_bounds__(256) void scan_kernel(
    const int*   __restrict__ seq,
    const float* __restrict__ Ktab,
    const float* __restrict__ rden,
    const float* __restrict__ Gtab,
    float*       __restrict__ ctx)
{
    const int bm  = blockIdx.x;      // 0..255
    const int b   = bm >> 1;
    const int mm  = bm & 1;
    const int tid = threadIdx.x;
    const int l   = tid & 63;
    const int wave = tid >> 6;
    const int rloc = l >> 3;         // 0..7
    const int cg   = l & 7;          // column group
    const int row  = wave*8 + rloc;  // 0..31
    const int cg4  = cg << 2;

    __shared__ float kt[VOC * HALF];     // 8 KB
    __shared__ float Gs[VOC * VOC];      // 16 KB
    __shared__ float rds[VOC];           // 256 B
    __shared__ int   sq[SEQLEN + 8];     // 8 KB + pad

    {
        const float4* Ksrc = (const float4*)(Ktab + mm*VOC*HALF);
        float4* Kdst = (float4*)kt;
        #pragma unroll
        for (int k = 0; k < 2; ++k) Kdst[tid + 256*k] = Ksrc[tid + 256*k];
        const float4* Gsrc = (const float4*)(Gtab + mm*VOC*VOC);
        float4* Gdst = (float4*)Gs;
        #pragma unroll
        for (int k = 0; k < 4; ++k) Gdst[tid + 256*k] = Gsrc[tid + 256*k];
        if (tid < VOC) rds[tid] = rden[mm*VOC + tid];
        const int* seqb = seq + b*SEQLEN;
        const int4* Ssrc = (const int4*)seqb;
        int4* Sdst = (int4*)sq;
        #pragma unroll
        for (int k = 0; k < 2; ++k) Sdst[tid + 256*k] = Ssrc[tid + 256*k];
        if (tid < 8) sq[SEQLEN + tid] = seqb[SEQLEN - 1];   // pad: clamp reads
    }
    __syncthreads();

    float m[4] = {0.f, 0.f, 0.f, 0.f};
    float kb0[4], kb1[4], kb2[4], kb3[4], kb4[4], kb5[4];

    const float dw = mm ? (1.0f / (float)SEQLEN) : 0.0f;
    float w0v = mm ? (1.0f / (float)SEQLEN) : 1.0f;
    float w1v = w0v + dw;
    float w2  = w0v + 2.f*dw;        // rolling w_{t+2}

    int v0 = sq[0], v1 = sq[1], v2 = sq[2], v3 = sq[3], v4 = sq[4], v5 = sq[5];

#define LOADK(B, vv)                                                    \
    { const float4 f_ = *(const float4*)(kt + ((vv) << 5) + cg4);       \
      B[0] = f_.x; B[1] = f_.y; B[2] = f_.z; B[3] = f_.w; }

    LOADK(kb0, v0); LOADK(kb1, v1); LOADK(kb2, v2); LOADK(kb3, v3); LOADK(kb4, v4);

    // pipeline registers
    float coefP = 0.f, coefPP = 0.f;
    float P1cur = 0.f, Dprev1 = 0.f, Dprev2 = 0.f;
    float gcur = 0.f, gcurN = Gs[(v0 << 6) + v1];
    float gA   = 0.f, gAn   = 0.f;
    float gB   = 0.f, gBn   = Gs[(v0 << 6) + v2];
    float kiw  = kt[(v0 << 5) + row] * w0v;
    float kiwN = kt[(v1 << 5) + row] * w1v;
    float rdw  = rds[v0] * w0v;
    float rdwN = rds[v1] * w1v;

    int t = 0;

// BU = k_t (update), BD = k_{t+3} (dot), BL <- k_{t+5} (load)
#define SCAN_BODY(BU, BD, BL)                                           \
    do {                                                                \
        /* critical recurrence */                                       \
        float p_    = fmaf(coefP, gcur, P1cur);                         \
        float coef_ = fmaf(-p_, rdw, kiw);                              \
        /* fold corrections for step t+1 (uses 2-body-old dot) */       \
        float P2x_  = fmaf(coefPP, gA, Dprev2);                         \
        float P1n_  = fmaf(coefP,  gB, P2x_);                           \
        /* raw dot D_t = m_{t-1} . k_{t+3} */                           \
        float a_ = m[0]*BD[0];                                          \
        a_ = fmaf(m[1], BD[1], a_);                                     \
        a_ = fmaf(m[2], BD[2], a_);                                     \
        a_ = fmaf(m[3], BD[3], a_);                                     \
        a_ += __shfl_xor(a_, 1);                                        \
        a_ += __shfl_xor(a_, 2);                                        \
        a_ += __shfl_xor(a_, 4);                                        \
        /* state update */                                              \
        m[0] = fmaf(coef_, BU[0], m[0]);                                \
        m[1] = fmaf(coef_, BU[1], m[1]);                                \
        m[2] = fmaf(coef_, BU[2], m[2]);                                \
        m[3] = fmaf(coef_, BU[3], m[3]);                                \
        /* prefetch k_{t+5} */                                          \
        LOADK(BL, v5);                                                  \
        /* scalar preps for body t+2 */                                 \
        const int s1_ = v1 << 6;                                        \
        float gcur2_ = Gs[s1_ + v2];                                    \
        float gA2_   = Gs[(v0 << 6) + v3];                              \
        float gB2_   = Gs[s1_ + v3];                                    \
        float kiw2_  = kt[(v2 << 5) + row] * w2;                        \
        float rdw2_  = rds[v2] * w2;                                    \
        int vnew_ = sq[t + 6];                                          \
        w2 += dw;                                                       \
        /* rotate pipeline */                                           \
        coefPP = coefP; coefP = coef_;                                  \
        P1cur = P1n_;                                                   \
        Dprev2 = Dprev1; Dprev1 = a_;                                   \
        gcur = gcurN; gcurN = gcur2_;                                   \
        gA = gAn; gAn = gA2_;                                           \
        gB = gBn; gBn = gB2_;                                           \
        kiw = kiwN; kiwN = kiw2_;                                       \
        rdw = rdwN; rdwN = rdw2_;                                       \
        v0 = v1; v1 = v2; v2 = v3; v3 = v4; v4 = v5; v5 = vnew_;        \
        ++t;                                                            \
    } while (0)

    // 2047 bodies = 341*6 + 1
    for (int it = 0; it < 341; ++it) {
        SCAN_BODY(kb0, kb3, kb5);
        SCAN_BODY(kb1, kb4, kb0);
        SCAN_BODY(kb2, kb5, kb1);
        SCAN_BODY(kb3, kb0, kb2);
        SCAN_BODY(kb4, kb1, kb3);
        SCAN_BODY(kb5, kb2, kb4);
    }
    SCAN_BODY(kb0, kb3, kb5);   // t = 2046
#undef SCAN_BODY
#undef LOADK

    // query: fresh dot against final m (exact)
    {
        const int vq = sq[SEQLEN - 1];
        const float4 kq = *(const float4*)(kt + (vq << 5) + cg4);
        float a = m[0]*kq.x;
        a = fmaf(m[1], kq.y, a);
        a = fmaf(m[2], kq.z, a);
        a = fmaf(m[3], kq.w, a);
        a += __shfl_xor(a, 1);
        a += __shfl_xor(a, 2);
        a += __shfl_xor(a, 4);
        if (cg == 0) ctx[b*64 + mm*32 + row] = a;
    }
}

// ---------------------------------------------------------------------------
// Kernel 3: out = ctx @ Wo + bo.
// ---------------------------------------------------------------------------
__global__ __launch_bounds__(64) void out_kernel(
    const float* __restrict__ ctx, const float* __restrict__ Wo,
    const float* __restrict__ bo,  float* __restrict__ out)
{
    const int b = blockIdx.x;
    const int o = threadIdx.x;
    float acc = bo[o];
    #pragma unroll
    for (int i = 0; i < 64; ++i) acc = fmaf(ctx[b*64 + i], Wo[i*64 + o], acc);
    out[b*64 + o] = acc;
}

extern "C" void kernel_launch(void* const* d_in, const int* in_sizes, int n_in,
                              void* d_out, int out_size, void* d_ws, size_t ws_size,
                              hipStream_t stream)
{
    const int*   seq   = (const int*)  d_in[0];
    const float* embed = (const float*)d_in[1];
    const float* W1    = (const float*)d_in[2];
    const float* b1    = (const float*)d_in[3];
    const float* W2    = (const float*)d_in[4];
    const float* b2    = (const float*)d_in[5];
    const float* ln_g  = (const float*)d_in[6];
    const float* ln_b  = (const float*)d_in[7];
    const float* Ws    = (const float*)d_in[8];
    const float* bs    = (const float*)d_in[9];
    const float* We    = (const float*)d_in[10];
    const float* be    = (const float*)d_in[11];
    const float* Wo    = (const float*)d_in[12];
    const float* bo    = (const float*)d_in[13];
    float* out = (float*)d_out;

    float* Ktab = (float*)d_ws;                 // 2*64*32
    float* rden = Ktab + 2*VOC*HALF;            // 2*64
    float* ctx  = rden + 2*VOC;                 // 128*64
    float* Gtab = ctx  + BATCH*64;              // 2*64*64

    build_table_kernel<<<VOC, 64, 0, stream>>>(embed, W1, b1, W2, b2, ln_g, ln_b,
                                               Ws, bs, We, be, Ktab, rden);
    gram_kernel<<<2, 64, 0, stream>>>(Ktab, Gtab);
    scan_kernel<<<BATCH*2, 256, 0, stream>>>(seq, Ktab, rden, Gtab, ctx);
    out_kernel<<<BATCH, 64, 0, stream>>>(ctx, Wo, bo, out);
}

// Round 4
// 240.467 us; speedup vs baseline: 1.8190x; 1.0816x over previous
//
#include <hip/hip_runtime.h>

#define HD      64
#define VOC     64
#define HALF    32
#define BATCH   128
#define SEQLEN  2048
#define NREC    2064   // records per (b,mm): covers max index 2052, 16-aligned

// ---------------------------------------------------------------------------
// cross-lane helpers: quad DPP adds (VALU) + xor-4 swizzle (1 DS op)
// ---------------------------------------------------------------------------
__device__ __forceinline__ float dpp_add_xor1(float x) {
    int y = __builtin_amdgcn_mov_dpp(__float_as_int(x), 0xB1, 0xF, 0xF, true); // quad_perm [1,0,3,2]
    return x + __int_as_float(y);
}
__device__ __forceinline__ float dpp_add_xor2(float x) {
    int y = __builtin_amdgcn_mov_dpp(__float_as_int(x), 0x4E, 0xF, 0xF, true); // quad_perm [2,3,0,1]
    return x + __int_as_float(y);
}
__device__ __forceinline__ float swz_xor4(float x) {
    return __int_as_float(__builtin_amdgcn_ds_swizzle(__float_as_int(x), 0x101F)); // xor 4
}

// ---------------------------------------------------------------------------
// Kernel 1: per-vocab table (unchanged; verified R1-R3).
// ---------------------------------------------------------------------------
__global__ __launch_bounds__(64) void build_table_kernel(
    const float* __restrict__ embed, const float* __restrict__ W1, const float* __restrict__ b1,
    const float* __restrict__ W2,    const float* __restrict__ b2,
    const float* __restrict__ ln_g,  const float* __restrict__ ln_b,
    const float* __restrict__ Ws,    const float* __restrict__ bs,
    const float* __restrict__ We,    const float* __restrict__ be,
    float* __restrict__ Ktab, float* __restrict__ rden)
{
    const int v = blockIdx.x;
    const int j = threadIdx.x;

    __shared__ float e_s[64];
    __shared__ float u_s[128];
    __shared__ float h_s[64];

    float e = embed[v*HD + j];
    e_s[j] = e;
    __syncthreads();

    float u0 = b1[j], u1 = b1[j + 64];
    #pragma unroll
    for (int i = 0; i < 64; ++i) {
        float ei = e_s[i];
        u0 = fmaf(ei, W1[i*128 + j],      u0);
        u1 = fmaf(ei, W1[i*128 + 64 + j], u1);
    }
    u_s[j]      = fmaxf(u0, 0.f);
    u_s[j + 64] = fmaxf(u1, 0.f);
    __syncthreads();

    float ff = b2[j];
    #pragma unroll
    for (int c = 0; c < 128; ++c) ff = fmaf(u_s[c], W2[c*64 + j], ff);

    float x = e + ff;
    float mu = x;
    #pragma unroll
    for (int m = 32; m; m >>= 1) mu += __shfl_xor(mu, m, 64);
    mu *= (1.f / 64.f);
    float d = x - mu;
    float var = d * d;
    #pragma unroll
    for (int m = 32; m; m >>= 1) var += __shfl_xor(var, m, 64);
    var *= (1.f / 64.f);
    float h = d * rsqrtf(var + 1e-5f) * ln_g[j] + ln_b[j];
    h_s[j] = h;
    __syncthreads();

    const int mm = j >> 5;
    const int jj = j & 31;
    const float* W  = mm ? We : Ws;
    float acc = mm ? be[jj] : bs[jj];
    #pragma unroll
    for (int i = 0; i < 64; ++i) acc = fmaf(h_s[i], W[i*32 + jj], acc);
    Ktab[(mm*VOC + v)*HALF + jj] = acc;

    float s = acc * acc;
    #pragma unroll
    for (int m = 16; m; m >>= 1) s += __shfl_xor(s, m, 32);
    if (jj == 0) rden[mm*VOC + v] = 1.f / (s + 1e-6f);
}

// ---------------------------------------------------------------------------
// Kernel 1b: gram table G[mm][v1][v2] = k_{v1} . k_{v2}
// ---------------------------------------------------------------------------
__global__ __launch_bounds__(64) void gram_kernel(
    const float* __restrict__ Ktab, float* __restrict__ Gtab)
{
    const int mm = blockIdx.x;
    const int j  = threadIdx.x;
    __shared__ float kt[VOC * HALF];
    for (int idx = j; idx < VOC * HALF; idx += 64) kt[idx] = Ktab[mm*VOC*HALF + idx];
    __syncthreads();
    for (int v1 = 0; v1 < VOC; ++v1) {
        float s0 = 0.f, s1 = 0.f;
        #pragma unroll
        for (int c = 0; c < 32; c += 2) {
            s0 = fmaf(kt[v1*HALF + c],     kt[j*HALF + c],     s0);
            s1 = fmaf(kt[v1*HALF + c + 1], kt[j*HALF + c + 1], s1);
        }
        Gtab[(mm*VOC + v1)*VOC + j] = s0 + s1;
    }
}

// ---------------------------------------------------------------------------
// Kernel 1c: per-step record stream. record(tau) for (b,mm):
//   a = { gc = G[v(t-1),v(t)], gA = G[v(t-2),v(t+1)], gB = G[v(t-1),v(t+1)], rdw = rd[v(t)]*w(t) }
//   b = { w(t), asfloat(v(t+3)<<5), 0, 0 }
// Index map verified against R3's (passing) rotation.
// ---------------------------------------------------------------------------
__global__ __launch_bounds__(256) void rec_kernel(
    const int*   __restrict__ seq,
    const float* __restrict__ Gtab,
    const float* __restrict__ rden,
    float*       __restrict__ recs)
{
    const int bm = blockIdx.x;     // 0..255
    const int b  = bm >> 1;
    const int mm = bm & 1;
    const int tid = threadIdx.x;

    __shared__ float Gsh[VOC * VOC];   // 16 KB
    __shared__ int   sqs[SEQLEN];      // 8 KB
    __shared__ float rdsh[VOC];

    {
        const float4* Gsrc = (const float4*)(Gtab + mm*VOC*VOC);
        float4* Gd = (float4*)Gsh;
        #pragma unroll
        for (int k = 0; k < 4; ++k) Gd[tid + 256*k] = Gsrc[tid + 256*k];
        const int4* Ss = (const int4*)(seq + b*SEQLEN);
        int4* Sd = (int4*)sqs;
        #pragma unroll
        for (int k = 0; k < 2; ++k) Sd[tid + 256*k] = Ss[tid + 256*k];
        if (tid < VOC) rdsh[tid] = rden[mm*VOC + tid];
    }
    __syncthreads();

    const float inv = 1.0f / (float)SEQLEN;
    float4* out = (float4*)recs + (size_t)bm * (NREC * 2);

    for (int rep = 0; rep < 9; ++rep) {
        int tau = tid + rep * 256;
        if (tau >= NREC) break;
        int xm1 = tau-1 < 0 ? 0 : (tau-1 > SEQLEN-1 ? SEQLEN-1 : tau-1);
        int xm2 = tau-2 < 0 ? 0 : (tau-2 > SEQLEN-1 ? SEQLEN-1 : tau-2);
        int x0  = tau   > SEQLEN-1 ? SEQLEN-1 : tau;
        int xp1 = tau+1 > SEQLEN-1 ? SEQLEN-1 : tau+1;
        int xp3 = tau+3 > SEQLEN-1 ? SEQLEN-1 : tau+3;
        int vm1 = sqs[xm1], vm2 = sqs[xm2], v0 = sqs[x0], vp1 = sqs[xp1], vp3 = sqs[xp3];
        int tc = tau > SEQLEN-2 ? SEQLEN-2 : tau;
        float w = mm ? (float)(tc + 1) * inv : 1.0f;
        float4 ra, rb;
        ra.x = Gsh[vm1*VOC + v0];
        ra.y = Gsh[vm2*VOC + vp1];
        ra.z = Gsh[vm1*VOC + vp1];
        ra.w = rdsh[v0] * w;
        rb.x = w;
        rb.y = __int_as_float(vp3 << 5);
        rb.z = 0.f; rb.w = 0.f;
        out[tau*2]     = ra;
        out[tau*2 + 1] = rb;
    }
}

// ---------------------------------------------------------------------------
// Kernel 2: the scan. 256 blocks x 256 threads; wave = 8 chains (rows) of one
// (b,mm); 8 lanes/chain, 4 cols/lane. LDS holds ONLY kt (8 KB).
// Per body per wave: 1 ds_read_b128 (k slice, broadcast) + 1 ds_read_b32 (k_row)
// + 1 ds_swizzle (xor4) + 2 uniform global_load_dwordx4 (record reload).
// ---------------------------------------------------------------------------
__global__ __launch_bounds__(256) void scan_kernel(
    const int*   __restrict__ seq,
    const float* __restrict__ Ktab,
    const float* __restrict__ recs,
    float*       __restrict__ ctx)
{
    const int bm  = blockIdx.x;      // 0..255
    const int b   = bm >> 1;
    const int mm  = bm & 1;
    const int tid = threadIdx.x;
    const int lane  = tid & 63;
    const int wave  = tid >> 6;
    const int chain = lane >> 3;          // 0..7
    const int cg    = lane & 7;           // col group
    const int row   = wave*8 + chain;     // 0..31
    const int cg4   = cg << 2;

    __shared__ float kt[VOC * HALF];      // 8 KB

    {
        const float4* Ks = (const float4*)(Ktab + mm*VOC*HALF);
        float4* Kd = (float4*)kt;
        Kd[tid]       = Ks[tid];
        Kd[tid + 256] = Ks[tid + 256];
    }
    __syncthreads();

    // record slots 0..5 preloaded with records 0..5
    const float4* rbase = (const float4*)recs + (size_t)bm * (NREC * 2);
    float4 rA0 = rbase[0],  rB0 = rbase[1];
    float4 rA1 = rbase[2],  rB1 = rbase[3];
    float4 rA2 = rbase[4],  rB2 = rbase[5];
    float4 rA3 = rbase[6],  rB3 = rbase[7];
    float4 rA4 = rbase[8],  rB4 = rbase[9];
    float4 rA5 = rbase[10], rB5 = rbase[11];

    // prologue token ids (one-time global reads)
    const int* sqp = seq + b*SEQLEN;
    const int v0 = sqp[0], v1 = sqp[1], v2 = sqp[2], v3 = sqp[3], v4 = sqp[4];

    float4 kb0 = *(const float4*)(kt + (v0 << 5) + cg4);
    float4 kb1 = *(const float4*)(kt + (v1 << 5) + cg4);
    float4 kb2 = *(const float4*)(kt + (v2 << 5) + cg4);
    float4 kb3 = *(const float4*)(kt + (v3 << 5) + cg4);
    float4 kb4 = *(const float4*)(kt + (v4 << 5) + cg4);
    float4 kb5;

    const float inv = 1.0f / (float)SEQLEN;
    const float dw  = mm ? inv : 0.0f;
    float w3 = mm ? 4.0f*inv : 1.0f;      // rolling w_{t+3}

    float kw0 = kt[(v0 << 5) + row] * (mm ? 1.0f*inv : 1.0f);
    float kw1 = kt[(v1 << 5) + row] * (mm ? 2.0f*inv : 1.0f);
    float kw2 = kt[(v2 << 5) + row] * (mm ? 3.0f*inv : 1.0f);
    float kw3, kw4, kw5;

    float m0 = 0.f, m1 = 0.f, m2 = 0.f, m3 = 0.f;
    float c0 = 0.f, c1 = 0.f, c2 = 0.f;       // positional coefs (period 3)
    float d0 = 0.f, d1 = 0.f, d2 = 0.f;       // positional raw dots (period 3)
    float P1 = 0.f;

// Body for step T. RA/RB = this slot's record (consumed, then reloaded with T+6).
// BU = k_T, BD = k_{T+3}, BL <- k_{T+5} (vt from RBV = slot (i+2)%6's RB).
// KWc consumed kiw(T); KWn <- kiw(T+3) (vt from THIS slot's RB = v_{T+3}).
// CW = c_T written; C1 = c_{T-1}; C2 = c_{T-2}. DW = D_T written; DR = D_{T-2}.
#define BODY(T, RA, RB, BU, BD, BL, RBV, KWc, KWn, CW, C1, C2, DW, DR)         \
    {                                                                          \
        float p_   = fmaf(C1, RA.x, P1);                                       \
        CW         = fmaf(-p_, RA.w, KWc);                                     \
        float P2x_ = fmaf(C2, RA.y, DR);                                       \
        P1         = fmaf(C1, RA.z, P2x_);                                     \
        float a_ = m0 * BD.x;                                                  \
        a_ = fmaf(m1, BD.y, a_);                                               \
        a_ = fmaf(m2, BD.z, a_);                                               \
        a_ = fmaf(m3, BD.w, a_);                                               \
        a_ = dpp_add_xor1(a_);                                                 \
        a_ = dpp_add_xor2(a_);                                                 \
        float o_ = swz_xor4(a_);                                               \
        m0 = fmaf(CW, BU.x, m0);                                               \
        m1 = fmaf(CW, BU.y, m1);                                               \
        m2 = fmaf(CW, BU.z, m2);                                               \
        m3 = fmaf(CW, BU.w, m3);                                               \
        DW = a_ + o_;                                                          \
        BL = *(const float4*)(kt + __float_as_int(RBV.y) + cg4);               \
        KWn = kt[__float_as_int(RB.y) + row] * w3;                             \
        w3 += dw;                                                              \
        const float4* rp_ = rbase + ((T) + 6) * 2;                             \
        RA = rp_[0];                                                           \
        RB = rp_[1];                                                           \
    }

    for (int n = 0; n < 341; ++n) {
        const int t6 = n * 6;
        BODY(t6+0, rA0,rB0, kb0,kb3,kb5, rB2, kw0,kw3, c0,c2,c1, d0,d1);
        BODY(t6+1, rA1,rB1, kb1,kb4,kb0, rB3, kw1,kw4, c1,c0,c2, d1,d2);
        BODY(t6+2, rA2,rB2, kb2,kb5,kb1, rB4, kw2,kw5, c2,c1,c0, d2,d0);
        BODY(t6+3, rA3,rB3, kb3,kb0,kb2, rB5, kw3,kw0, c0,c2,c1, d0,d1);
        BODY(t6+4, rA4,rB4, kb4,kb1,kb3, rB0, kw4,kw1, c1,c0,c2, d1,d2);
        BODY(t6+5, rA5,rB5, kb5,kb2,kb4, rB1, kw5,kw2, c2,c1,c0, d2,d0);
    }
    BODY(2046, rA0,rB0, kb0,kb3,kb5, rB2, kw0,kw3, c0,c2,c1, d0,d1);
#undef BODY

    // query: p_q = P1_final + c_2046 * G[v_2046, v_2047]; slot 1 holds record 2047.
    float pq = fmaf(c0, rA1.x, P1);
    if (cg == 0) ctx[b*64 + mm*32 + row] = pq;
}

// ---------------------------------------------------------------------------
// Kernel 3: out = ctx @ Wo + bo.
// ---------------------------------------------------------------------------
__global__ __launch_bounds__(64) void out_kernel(
    const float* __restrict__ ctx, const float* __restrict__ Wo,
    const float* __restrict__ bo,  float* __restrict__ out)
{
    const int b = blockIdx.x;
    const int o = threadIdx.x;
    float acc = bo[o];
    #pragma unroll
    for (int i = 0; i < 64; ++i) acc = fmaf(ctx[b*64 + i], Wo[i*64 + o], acc);
    out[b*64 + o] = acc;
}

extern "C" void kernel_launch(void* const* d_in, const int* in_sizes, int n_in,
                              void* d_out, int out_size, void* d_ws, size_t ws_size,
                              hipStream_t stream)
{
    const int*   seq   = (const int*)  d_in[0];
    const float* embed = (const float*)d_in[1];
    const float* W1    = (const float*)d_in[2];
    const float* b1    = (const float*)d_in[3];
    const float* W2    = (const float*)d_in[4];
    const float* b2    = (const float*)d_in[5];
    const float* ln_g  = (const float*)d_in[6];
    const float* ln_b  = (const float*)d_in[7];
    const float* Ws    = (const float*)d_in[8];
    const float* bs    = (const float*)d_in[9];
    const float* We    = (const float*)d_in[10];
    const float* be    = (const float*)d_in[11];
    const float* Wo    = (const float*)d_in[12];
    const float* bo    = (const float*)d_in[13];
    float* out = (float*)d_out;

    // ws layout (floats): recs stream first (32B-aligned records), then tables
    float* recs = (float*)d_ws;                       // 256*2064*8 floats = 16.9 MB
    float* Ktab = recs + (size_t)256*NREC*8;          // 2*64*32
    float* rden = Ktab + 2*VOC*HALF;                  // 2*64
    float* Gtab = rden + 2*VOC;                       // 2*64*64
    float* ctx  = Gtab + 2*VOC*VOC;                   // 128*64

    build_table_kernel<<<VOC, 64, 0, stream>>>(embed, W1, b1, W2, b2, ln_g, ln_b,
                                               Ws, bs, We, be, Ktab, rden);
    gram_kernel<<<2, 64, 0, stream>>>(Ktab, Gtab);
    rec_kernel<<<BATCH*2, 256, 0, stream>>>(seq, Gtab, rden, recs);
    scan_kernel<<<BATCH*2, 256, 0, stream>>>(seq, Ktab, recs, ctx);
    out_kernel<<<BATCH, 64, 0, stream>>>(ctx, Wo, bo, out);
}

// Round 5
// 237.299 us; speedup vs baseline: 1.8433x; 1.0134x over previous
//
#include <hip/hip_runtime.h>

#define HD      64
#define VOC     64
#define HALF    32
#define BATCH   128
#define SEQLEN  2048
#define NREC    2064   // records per (b,mm): covers max reload index 2058, 16-aligned

// ---------------------------------------------------------------------------
// cross-lane helpers: quad DPP adds (VALU) + xor-4 swizzle (1 DS op)
// ---------------------------------------------------------------------------
__device__ __forceinline__ float dpp_add_xor1(float x) {
    int y = __builtin_amdgcn_mov_dpp(__float_as_int(x), 0xB1, 0xF, 0xF, true); // quad_perm [1,0,3,2]
    return x + __int_as_float(y);
}
__device__ __forceinline__ float dpp_add_xor2(float x) {
    int y = __builtin_amdgcn_mov_dpp(__float_as_int(x), 0x4E, 0xF, 0xF, true); // quad_perm [2,3,0,1]
    return x + __int_as_float(y);
}
__device__ __forceinline__ float swz_xor4(float x) {
    return __int_as_float(__builtin_amdgcn_ds_swizzle(__float_as_int(x), 0x101F)); // xor 4
}

// ---------------------------------------------------------------------------
// Kernel 1: per-vocab table (unchanged; verified R1-R4).
// ---------------------------------------------------------------------------
__global__ __launch_bounds__(64) void build_table_kernel(
    const float* __restrict__ embed, const float* __restrict__ W1, const float* __restrict__ b1,
    const float* __restrict__ W2,    const float* __restrict__ b2,
    const float* __restrict__ ln_g,  const float* __restrict__ ln_b,
    const float* __restrict__ Ws,    const float* __restrict__ bs,
    const float* __restrict__ We,    const float* __restrict__ be,
    float* __restrict__ Ktab, float* __restrict__ rden)
{
    const int v = blockIdx.x;
    const int j = threadIdx.x;

    __shared__ float e_s[64];
    __shared__ float u_s[128];
    __shared__ float h_s[64];

    float e = embed[v*HD + j];
    e_s[j] = e;
    __syncthreads();

    float u0 = b1[j], u1 = b1[j + 64];
    #pragma unroll
    for (int i = 0; i < 64; ++i) {
        float ei = e_s[i];
        u0 = fmaf(ei, W1[i*128 + j],      u0);
        u1 = fmaf(ei, W1[i*128 + 64 + j], u1);
    }
    u_s[j]      = fmaxf(u0, 0.f);
    u_s[j + 64] = fmaxf(u1, 0.f);
    __syncthreads();

    float ff = b2[j];
    #pragma unroll
    for (int c = 0; c < 128; ++c) ff = fmaf(u_s[c], W2[c*64 + j], ff);

    float x = e + ff;
    float mu = x;
    #pragma unroll
    for (int m = 32; m; m >>= 1) mu += __shfl_xor(mu, m, 64);
    mu *= (1.f / 64.f);
    float d = x - mu;
    float var = d * d;
    #pragma unroll
    for (int m = 32; m; m >>= 1) var += __shfl_xor(var, m, 64);
    var *= (1.f / 64.f);
    float h = d * rsqrtf(var + 1e-5f) * ln_g[j] + ln_b[j];
    h_s[j] = h;
    __syncthreads();

    const int mm = j >> 5;
    const int jj = j & 31;
    const float* W  = mm ? We : Ws;
    float acc = mm ? be[jj] : bs[jj];
    #pragma unroll
    for (int i = 0; i < 64; ++i) acc = fmaf(h_s[i], W[i*32 + jj], acc);
    Ktab[(mm*VOC + v)*HALF + jj] = acc;

    float s = acc * acc;
    #pragma unroll
    for (int m = 16; m; m >>= 1) s += __shfl_xor(s, m, 32);
    if (jj == 0) rden[mm*VOC + v] = 1.f / (s + 1e-6f);
}

// ---------------------------------------------------------------------------
// Kernel 1b: gram table G[mm][v1][v2] = k_{v1} . k_{v2}
// ---------------------------------------------------------------------------
__global__ __launch_bounds__(64) void gram_kernel(
    const float* __restrict__ Ktab, float* __restrict__ Gtab)
{
    const int mm = blockIdx.x;
    const int j  = threadIdx.x;
    __shared__ float kt[VOC * HALF];
    for (int idx = j; idx < VOC * HALF; idx += 64) kt[idx] = Ktab[mm*VOC*HALF + idx];
    __syncthreads();
    for (int v1 = 0; v1 < VOC; ++v1) {
        float s0 = 0.f, s1 = 0.f;
        #pragma unroll
        for (int c = 0; c < 32; c += 2) {
            s0 = fmaf(kt[v1*HALF + c],     kt[j*HALF + c],     s0);
            s1 = fmaf(kt[v1*HALF + c + 1], kt[j*HALF + c + 1], s1);
        }
        Gtab[(mm*VOC + v1)*VOC + j] = s0 + s1;
    }
}

// ---------------------------------------------------------------------------
// Kernel 1c: per-step record stream (unchanged from R4; verified).
//   a = { G[v(t-1),v(t)], G[v(t-2),v(t+1)], G[v(t-1),v(t+1)], rd[v(t)]*w(t) }
//   b = { w(t), asfloat(v(t+3)<<5), 0, 0 }
// ---------------------------------------------------------------------------
__global__ __launch_bounds__(256) void rec_kernel(
    const int*   __restrict__ seq,
    const float* __restrict__ Gtab,
    const float* __restrict__ rden,
    float*       __restrict__ recs)
{
    const int bm = blockIdx.x;
    const int b  = bm >> 1;
    const int mm = bm & 1;
    const int tid = threadIdx.x;

    __shared__ float Gsh[VOC * VOC];
    __shared__ int   sqs[SEQLEN];
    __shared__ float rdsh[VOC];

    {
        const float4* Gsrc = (const float4*)(Gtab + mm*VOC*VOC);
        float4* Gd = (float4*)Gsh;
        #pragma unroll
        for (int k = 0; k < 4; ++k) Gd[tid + 256*k] = Gsrc[tid + 256*k];
        const int4* Ss = (const int4*)(seq + b*SEQLEN);
        int4* Sd = (int4*)sqs;
        #pragma unroll
        for (int k = 0; k < 2; ++k) Sd[tid + 256*k] = Ss[tid + 256*k];
        if (tid < VOC) rdsh[tid] = rden[mm*VOC + tid];
    }
    __syncthreads();

    const float inv = 1.0f / (float)SEQLEN;
    float4* out = (float4*)recs + (size_t)bm * (NREC * 2);

    for (int rep = 0; rep < 9; ++rep) {
        int tau = tid + rep * 256;
        if (tau >= NREC) break;
        int xm1 = tau-1 < 0 ? 0 : (tau-1 > SEQLEN-1 ? SEQLEN-1 : tau-1);
        int xm2 = tau-2 < 0 ? 0 : (tau-2 > SEQLEN-1 ? SEQLEN-1 : tau-2);
        int x0  = tau   > SEQLEN-1 ? SEQLEN-1 : tau;
        int xp1 = tau+1 > SEQLEN-1 ? SEQLEN-1 : tau+1;
        int xp3 = tau+3 > SEQLEN-1 ? SEQLEN-1 : tau+3;
        int vm1 = sqs[xm1], vm2 = sqs[xm2], v0 = sqs[x0], vp1 = sqs[xp1], vp3 = sqs[xp3];
        int tc = tau > SEQLEN-2 ? SEQLEN-2 : tau;
        float w = mm ? (float)(tc + 1) * inv : 1.0f;
        float4 ra, rb;
        ra.x = Gsh[vm1*VOC + v0];
        ra.y = Gsh[vm2*VOC + vp1];
        ra.z = Gsh[vm1*VOC + vp1];
        ra.w = rdsh[v0] * w;
        rb.x = w;
        rb.y = __int_as_float(vp3 << 5);
        rb.z = 0.f; rb.w = 0.f;
        out[tau*2]     = ra;
        out[tau*2 + 1] = rb;
    }
}

// ---------------------------------------------------------------------------
// Kernel 2: the scan. 256 blocks x 256 threads; wave = 8 rows of one (b,mm),
// 8 lanes/row, 4 cols/lane. LDS holds ONLY kt (8 KB).
// Records travel via VECTOR global loads (laundered address -> vmcnt, not
// lgkmcnt) in a 12-slot rotation: body T consumes record T, reloads T+12.
// ---------------------------------------------------------------------------
__global__ __launch_bounds__(256) void scan_kernel(
    const int*   __restrict__ seq,
    const float* __restrict__ Ktab,
    const float* __restrict__ recs,
    float*       __restrict__ ctx)
{
    const int bm  = blockIdx.x;
    const int b   = bm >> 1;
    const int mm  = bm & 1;
    const int tid = threadIdx.x;
    const int lane  = tid & 63;
    const int wave  = tid >> 6;
    const int chain = lane >> 3;
    const int cg    = lane & 7;
    const int row   = wave*8 + chain;
    const int cg4   = cg << 2;

    __shared__ float kt[VOC * HALF];      // 8 KB

    {
        const float4* Ks = (const float4*)(Ktab + mm*VOC*HALF);
        float4* Kd = (float4*)kt;
        Kd[tid]       = Ks[tid];
        Kd[tid + 256] = Ks[tid + 256];
    }
    __syncthreads();

    // opaque zero: forces record addresses to look divergent -> VMEM path
    int lz;
    asm volatile("v_mov_b32 %0, 0" : "=v"(lz));

    const float4* rbase = (const float4*)recs + (size_t)bm * (NREC * 2);
    const float4* rb_ = rbase + lz;
    float4 rA0  = rb_[0],  rB0  = rb_[1];
    float4 rA1  = rb_[2],  rB1  = rb_[3];
    float4 rA2  = rb_[4],  rB2  = rb_[5];
    float4 rA3  = rb_[6],  rB3  = rb_[7];
    float4 rA4  = rb_[8],  rB4  = rb_[9];
    float4 rA5  = rb_[10], rB5  = rb_[11];
    float4 rA6  = rb_[12], rB6  = rb_[13];
    float4 rA7  = rb_[14], rB7  = rb_[15];
    float4 rA8  = rb_[16], rB8  = rb_[17];
    float4 rA9  = rb_[18], rB9  = rb_[19];
    float4 rA10 = rb_[20], rB10 = rb_[21];
    float4 rA11 = rb_[22], rB11 = rb_[23];

    // prologue token ids (one-time global reads)
    const int* sqp = seq + b*SEQLEN;
    const int v0 = sqp[0], v1 = sqp[1], v2 = sqp[2], v3 = sqp[3], v4 = sqp[4];

    float4 kb0 = *(const float4*)(kt + (v0 << 5) + cg4);
    float4 kb1 = *(const float4*)(kt + (v1 << 5) + cg4);
    float4 kb2 = *(const float4*)(kt + (v2 << 5) + cg4);
    float4 kb3 = *(const float4*)(kt + (v3 << 5) + cg4);
    float4 kb4 = *(const float4*)(kt + (v4 << 5) + cg4);
    float4 kb5;

    const float inv = 1.0f / (float)SEQLEN;
    const float dw  = mm ? inv : 0.0f;
    float w3 = mm ? 4.0f*inv : 1.0f;      // rolling w_{t+3}

    float kw0 = kt[(v0 << 5) + row] * (mm ? 1.0f*inv : 1.0f);
    float kw1 = kt[(v1 << 5) + row] * (mm ? 2.0f*inv : 1.0f);
    float kw2 = kt[(v2 << 5) + row] * (mm ? 3.0f*inv : 1.0f);
    float kw3, kw4, kw5;

    float m0 = 0.f, m1 = 0.f, m2 = 0.f, m3 = 0.f;
    float c0 = 0.f, c1 = 0.f, c2 = 0.f;       // positional coefs (period 3)
    float d0 = 0.f, d1 = 0.f, d2 = 0.f;       // positional raw dots (period 3)
    float P1 = 0.f;

// Body for step T (slot = T%12). RA/RB consumed, then reloaded with T+12.
// BU = k_T, BD = k_{t+3}, BL <- k_{T+5} (vt from RBV = slot (T+2)%12's RB).
// KWc consumed kiw(T); KWn <- kiw(T+3) (vt from THIS slot's RB = v_{T+3}).
#define BODY(T, RA, RB, BU, BD, BL, RBV, KWc, KWn, CW, C1, C2, DW, DR)         \
    {                                                                          \
        float p_   = fmaf(C1, RA.x, P1);                                       \
        CW         = fmaf(-p_, RA.w, KWc);                                     \
        float P2x_ = fmaf(C2, RA.y, DR);                                       \
        P1         = fmaf(C1, RA.z, P2x_);                                     \
        float a_ = m0 * BD.x;                                                  \
        a_ = fmaf(m1, BD.y, a_);                                               \
        a_ = fmaf(m2, BD.z, a_);                                               \
        a_ = fmaf(m3, BD.w, a_);                                               \
        a_ = dpp_add_xor1(a_);                                                 \
        a_ = dpp_add_xor2(a_);                                                 \
        float o_ = swz_xor4(a_);                                               \
        m0 = fmaf(CW, BU.x, m0);                                               \
        m1 = fmaf(CW, BU.y, m1);                                               \
        m2 = fmaf(CW, BU.z, m2);                                               \
        m3 = fmaf(CW, BU.w, m3);                                               \
        DW = a_ + o_;                                                          \
        BL = *(const float4*)(kt + __float_as_int(RBV.y) + cg4);               \
        KWn = kt[__float_as_int(RB.y) + row] * w3;                             \
        w3 += dw;                                                              \
        const float4* rp_ = rbase + ((T) + 12) * 2 + lz;                       \
        RA = rp_[0];                                                           \
        RB = rp_[1];                                                           \
    }

    // 2047 bodies = 170*12 + 7
    for (int n = 0; n < 170; ++n) {
        const int t12 = n * 12;
        BODY(t12+0,  rA0, rB0,  kb0,kb3,kb5, rB2,  kw0,kw3, c0,c2,c1, d0,d1);
        BODY(t12+1,  rA1, rB1,  kb1,kb4,kb0, rB3,  kw1,kw4, c1,c0,c2, d1,d2);
        BODY(t12+2,  rA2, rB2,  kb2,kb5,kb1, rB4,  kw2,kw5, c2,c1,c0, d2,d0);
        BODY(t12+3,  rA3, rB3,  kb3,kb0,kb2, rB5,  kw3,kw0, c0,c2,c1, d0,d1);
        BODY(t12+4,  rA4, rB4,  kb4,kb1,kb3, rB6,  kw4,kw1, c1,c0,c2, d1,d2);
        BODY(t12+5,  rA5, rB5,  kb5,kb2,kb4, rB7,  kw5,kw2, c2,c1,c0, d2,d0);
        BODY(t12+6,  rA6, rB6,  kb0,kb3,kb5, rB8,  kw0,kw3, c0,c2,c1, d0,d1);
        BODY(t12+7,  rA7, rB7,  kb1,kb4,kb0, rB9,  kw1,kw4, c1,c0,c2, d1,d2);
        BODY(t12+8,  rA8, rB8,  kb2,kb5,kb1, rB10, kw2,kw5, c2,c1,c0, d2,d0);
        BODY(t12+9,  rA9, rB9,  kb3,kb0,kb2, rB11, kw3,kw0, c0,c2,c1, d0,d1);
        BODY(t12+10, rA10,rB10, kb4,kb1,kb3, rB0,  kw4,kw1, c1,c0,c2, d1,d2);
        BODY(t12+11, rA11,rB11, kb5,kb2,kb4, rB1,  kw5,kw2, c2,c1,c0, d2,d0);
    }
    // epilogue bodies 2040..2046
    BODY(2040, rA0, rB0, kb0,kb3,kb5, rB2, kw0,kw3, c0,c2,c1, d0,d1);
    BODY(2041, rA1, rB1, kb1,kb4,kb0, rB3, kw1,kw4, c1,c0,c2, d1,d2);
    BODY(2042, rA2, rB2, kb2,kb5,kb1, rB4, kw2,kw5, c2,c1,c0, d2,d0);
    BODY(2043, rA3, rB3, kb3,kb0,kb2, rB5, kw3,kw0, c0,c2,c1, d0,d1);
    BODY(2044, rA4, rB4, kb4,kb1,kb3, rB6, kw4,kw1, c1,c0,c2, d1,d2);
    BODY(2045, rA5, rB5, kb5,kb2,kb4, rB7, kw5,kw2, c2,c1,c0, d2,d0);
    BODY(2046, rA6, rB6, kb0,kb3,kb5, rB8, kw0,kw3, c0,c2,c1, d0,d1);
#undef BODY

    // query: p_q = P1 + c_2046 * G[v_2046, v_2047].
    // Record 2047 sits in slot 7 (reloaded at body 2035, never overwritten).
    float pq = fmaf(c0, rA7.x, P1);
    if (cg == 0) ctx[b*64 + mm*32 + row] = pq;
}

// ---------------------------------------------------------------------------
// Kernel 3: out = ctx @ Wo + bo.
// ---------------------------------------------------------------------------
__global__ __launch_bounds__(64) void out_kernel(
    const float* __restrict__ ctx, const float* __restrict__ Wo,
    const float* __restrict__ bo,  float* __restrict__ out)
{
    const int b = blockIdx.x;
    const int o = threadIdx.x;
    float acc = bo[o];
    #pragma unroll
    for (int i = 0; i < 64; ++i) acc = fmaf(ctx[b*64 + i], Wo[i*64 + o], acc);
    out[b*64 + o] = acc;
}

extern "C" void kernel_launch(void* const* d_in, const int* in_sizes, int n_in,
                              void* d_out, int out_size, void* d_ws, size_t ws_size,
                              hipStream_t stream)
{
    const int*   seq   = (const int*)  d_in[0];
    const float* embed = (const float*)d_in[1];
    const float* W1    = (const float*)d_in[2];
    const float* b1    = (const float*)d_in[3];
    const float* W2    = (const float*)d_in[4];
    const float* b2    = (const float*)d_in[5];
    const float* ln_g  = (const float*)d_in[6];
    const float* ln_b  = (const float*)d_in[7];
    const float* Ws    = (const float*)d_in[8];
    const float* bs    = (const float*)d_in[9];
    const float* We    = (const float*)d_in[10];
    const float* be    = (const float*)d_in[11];
    const float* Wo    = (const float*)d_in[12];
    const float* bo    = (const float*)d_in[13];
    float* out = (float*)d_out;

    float* recs = (float*)d_ws;                       // 256*2064*8 floats = 16.9 MB
    float* Ktab = recs + (size_t)256*NREC*8;
    float* rden = Ktab + 2*VOC*HALF;
    float* Gtab = rden + 2*VOC;
    float* ctx  = Gtab + 2*VOC*VOC;

    build_table_kernel<<<VOC, 64, 0, stream>>>(embed, W1, b1, W2, b2, ln_g, ln_b,
                                               Ws, bs, We, be, Ktab, rden);
    gram_kernel<<<2, 64, 0, stream>>>(Ktab, Gtab);
    rec_kernel<<<BATCH*2, 256, 0, stream>>>(seq, Gtab, rden, recs);
    scan_kernel<<<BATCH*2, 256, 0, stream>>>(seq, Ktab, recs, ctx);
    out_kernel<<<BATCH, 64, 0, stream>>>(ctx, Wo, bo, out);
}

// Round 7
// 132.405 us; speedup vs baseline: 3.3035x; 1.7922x over previous
//
#include <hip/hip_runtime.h>

#define HD      64
#define VOC     64
#define HALF    32
#define BATCH   128
#define SEQLEN  2048

// ---------------------------------------------------------------------------
// Kernel 1: per-vocab table (unchanged; verified R1-R5).
// ---------------------------------------------------------------------------
__global__ __launch_bounds__(64) void build_table_kernel(
    const float* __restrict__ embed, const float* __restrict__ W1, const float* __restrict__ b1,
    const float* __restrict__ W2,    const float* __restrict__ b2,
    const float* __restrict__ ln_g,  const float* __restrict__ ln_b,
    const float* __restrict__ Ws,    const float* __restrict__ bs,
    const float* __restrict__ We,    const float* __restrict__ be,
    float* __restrict__ Ktab, float* __restrict__ rden)
{
    const int v = blockIdx.x;
    const int j = threadIdx.x;

    __shared__ float e_s[64];
    __shared__ float u_s[128];
    __shared__ float h_s[64];

    float e = embed[v*HD + j];
    e_s[j] = e;
    __syncthreads();

    float u0 = b1[j], u1 = b1[j + 64];
    #pragma unroll
    for (int i = 0; i < 64; ++i) {
        float ei = e_s[i];
        u0 = fmaf(ei, W1[i*128 + j],      u0);
        u1 = fmaf(ei, W1[i*128 + 64 + j], u1);
    }
    u_s[j]      = fmaxf(u0, 0.f);
    u_s[j + 64] = fmaxf(u1, 0.f);
    __syncthreads();

    float ff = b2[j];
    #pragma unroll
    for (int c = 0; c < 128; ++c) ff = fmaf(u_s[c], W2[c*64 + j], ff);

    float x = e + ff;
    float mu = x;
    #pragma unroll
    for (int m = 32; m; m >>= 1) mu += __shfl_xor(mu, m, 64);
    mu *= (1.f / 64.f);
    float d = x - mu;
    float var = d * d;
    #pragma unroll
    for (int m = 32; m; m >>= 1) var += __shfl_xor(var, m, 64);
    var *= (1.f / 64.f);
    float h = d * rsqrtf(var + 1e-5f) * ln_g[j] + ln_b[j];
    h_s[j] = h;
    __syncthreads();

    const int mm = j >> 5;
    const int jj = j & 31;
    const float* W  = mm ? We : Ws;
    float acc = mm ? be[jj] : bs[jj];
    #pragma unroll
    for (int i = 0; i < 64; ++i) acc = fmaf(h_s[i], W[i*32 + jj], acc);
    Ktab[(mm*VOC + v)*HALF + jj] = acc;

    float s = acc * acc;
    #pragma unroll
    for (int m = 16; m; m >>= 1) s += __shfl_xor(s, m, 32);
    if (jj == 0) rden[mm*VOC + v] = 1.f / (s + 1e-6f);
}

// ---------------------------------------------------------------------------
// Kernel 1b: gram table G[mm][v1][v2] = k_{v1} . k_{v2} (symmetric).
// ---------------------------------------------------------------------------
__global__ __launch_bounds__(64) void gram_kernel(
    const float* __restrict__ Ktab, float* __restrict__ Gtab)
{
    const int mm = blockIdx.x;
    const int j  = threadIdx.x;
    __shared__ float kt[VOC * HALF];
    for (int idx = j; idx < VOC * HALF; idx += 64) kt[idx] = Ktab[mm*VOC*HALF + idx];
    __syncthreads();
    for (int v1 = 0; v1 < VOC; ++v1) {
        float s0 = 0.f, s1 = 0.f;
        #pragma unroll
        for (int c = 0; c < 32; c += 2) {
            s0 = fmaf(kt[v1*HALF + c],     kt[j*HALF + c],     s0);
            s1 = fmaf(kt[v1*HALF + c + 1], kt[j*HALF + c + 1], s1);
        }
        Gtab[(mm*VOC + v1)*VOC + j] = s0 + s1;
    }
}

// ---------------------------------------------------------------------------
// Kernel 2: chunked backward scan. One block per (batch, matrix) pair.
//
// Math: ctx = M_T q = sum_t w_t d_t k_t, d_t = k_t . z_t,
//       z_t = (prod_{s>t} A_s) q,  A_s = I - c_s k_s k_s^T,  c_s = w_s/den_s.
// Chunk [T0, T0+32): d = (I+R)^-1 K z_in, R_ts = c_s G[v_t,v_s] (s>t).
// W = (I+R)^-1 K depends only on token ids -> solved in parallel (4 waves,
// 4 chunks per round, register-resident W, unrolled back-substitution).
// Sequential part = 64 chunk applies: d = W z; z -= K^T(c*d); ctx += K^T(w*d).
// Key 2047 is a pad slot (c=w=0). q = kt[seq[2047]].
// ---------------------------------------------------------------------------
__global__ __launch_bounds__(256) void chunk_scan_kernel(
    const int*   __restrict__ seq,
    const float* __restrict__ Ktab,
    const float* __restrict__ rden,
    const float* __restrict__ Gtab,
    float*       __restrict__ ctxg)
{
    const int bm   = blockIdx.x;      // 0..255
    const int b    = bm >> 1;
    const int mm   = bm & 1;
    const int tid  = threadIdx.x;
    const int lane = tid & 63;
    const int wave = tid >> 6;
    const int col  = lane & 31;       // 0..31
    const int half = lane >> 5;       // 0..1 (row half)

    __shared__ float ktp[VOC * 33];        // padded kt: ktp[v*33+col]
    __shared__ float Gp [VOC * 65];        // padded gram: Gp[v1*65+v2]
    __shared__ float rd_s[VOC];
    __shared__ int   sq[SEQLEN];
    __shared__ float Wl[4][32 * 33];       // per-wave chunk W (padded)
    __shared__ float carr[4][32], warr[4][32];
    __shared__ float a_l[32], b_l[32], z_l[32], ctx_l[32];

    // ---- stage tables ----
    for (int idx = tid; idx < VOC*HALF; idx += 256) {
        int v = idx >> 5, c = idx & 31;
        ktp[v*33 + c] = Ktab[mm*VOC*HALF + idx];
    }
    for (int idx = tid; idx < VOC*VOC; idx += 256) {
        int v1 = idx >> 6, v2 = idx & 63;
        Gp[v1*65 + v2] = Gtab[mm*VOC*VOC + idx];
    }
    if (tid < VOC) rd_s[tid] = rden[mm*VOC + tid];
    {
        const int4* S = (const int4*)(seq + b*SEQLEN);
        int4* D = (int4*)sq;
        D[tid] = S[tid];
        D[tid + 256] = S[tid + 256];
    }
    __syncthreads();

    if (tid < 32) { z_l[tid] = ktp[sq[SEQLEN-1]*33 + tid]; ctx_l[tid] = 0.f; }
    __syncthreads();

    const float inv = 1.0f / (float)SEQLEN;

    for (int r = 0; r < 16; ++r) {
        const int base = 60 - 4*r;            // chunk-set, descending over rounds
        const int T0   = (base + wave) << 5;  // this wave's chunk start key

        // per-chunk scalars c_t, w_t (pad key 2047 -> 0)
        if (lane < 32) {
            int tg = T0 + lane;
            int v  = sq[tg];
            float wgt = mm ? (float)(tg + 1) * inv : 1.0f;
            if (tg == SEQLEN-1) wgt = 0.f;
            carr[wave][lane] = rd_s[v] * wgt;
            warr[wave][lane] = wgt;
        }
        __builtin_amdgcn_sched_barrier(0);

        // init W rows: lane (col,half) owns rows half*16+i
        float w_[16]; int vo[16];
        #pragma unroll
        for (int i = 0; i < 16; ++i) {
            vo[i] = sq[T0 + half*16 + i];
            w_[i] = ktp[vo[i]*33 + col];
        }
        __builtin_amdgcn_sched_barrier(0);

        // backward substitution: for s=31..1, W_t -= c_s G[v_t,v_s] W_s (t<s)
        #pragma unroll 31
        for (int s = 31; s >= 1; --s) {
            const int so = s >> 4, sl = s & 15;
            float sent = w_[sl];
            float got  = __shfl_xor(sent, 32);
            float sval = (half == so) ? sent : got;       // W_s[col], broadcast
            float csv  = carr[wave][s] * sval;
            const float* grow = &Gp[sq[T0 + s]*65];
            const int UB = (s < 16) ? s : 16;
            #pragma unroll
            for (int i = 0; i < UB; ++i) {
                float g   = grow[vo[i]];
                float upd = fmaf(-csv, g, w_[i]);
                bool act  = (half == 0) | ((16 + i) < s); // global row < s
                w_[i] = act ? upd : w_[i];
            }
        }

        // publish W
        #pragma unroll
        for (int i = 0; i < 16; ++i)
            Wl[wave][(half*16 + i)*33 + col] = w_[i];

        __syncthreads();

        // ---- sequential applies (wave 0), descending chunk order ----
        if (wave == 0) {
            for (int j = 3; j >= 0; --j) {
                const int T0j = (base + j) << 5;
                // d_t = sum_col W[t][col] z[col]   (lane: t=col idx, h2=col half)
                const int tl = col, h2 = half;
                float pg = 0.f;
                #pragma unroll
                for (int q2 = 0; q2 < 16; ++q2)
                    pg = fmaf(Wl[j][tl*33 + h2*16 + q2], z_l[h2*16 + q2], pg);
                float d  = pg + __shfl_xor(pg, 32);
                float al = carr[j][tl] * d;
                float bl = warr[j][tl] * d;
                if (h2 == 0) { a_l[tl] = al; b_l[tl] = bl; }
                __builtin_amdgcn_sched_barrier(0);
                // z[col] -= sum_t a_t kt[v_t][col]; ctx[col] += sum_t b_t kt[..]
                float pz = 0.f, pc = 0.f;
                #pragma unroll
                for (int i = 0; i < 16; ++i) {
                    int tg = T0j + h2*16 + i;
                    float kv = ktp[sq[tg]*33 + col];
                    pz = fmaf(a_l[h2*16 + i], kv, pz);
                    pc = fmaf(b_l[h2*16 + i], kv, pc);
                }
                float zo = __shfl_xor(pz, 32);
                float co = __shfl_xor(pc, 32);
                if (h2 == 0) {
                    z_l[col]   = z_l[col]   - (pz + zo);
                    ctx_l[col] = ctx_l[col] + (pc + co);
                }
                __builtin_amdgcn_sched_barrier(0);
            }
        }
        __syncthreads();
    }

    if (tid < 32) ctxg[b*64 + mm*32 + tid] = ctx_l[tid];
}

// ---------------------------------------------------------------------------
// Kernel 3: out = ctx @ Wo + bo.
// ---------------------------------------------------------------------------
__global__ __launch_bounds__(64) void out_kernel(
    const float* __restrict__ ctx, const float* __restrict__ Wo,
    const float* __restrict__ bo,  float* __restrict__ out)
{
    const int b = blockIdx.x;
    const int o = threadIdx.x;
    float acc = bo[o];
    #pragma unroll
    for (int i = 0; i < 64; ++i) acc = fmaf(ctx[b*64 + i], Wo[i*64 + o], acc);
    out[b*64 + o] = acc;
}

extern "C" void kernel_launch(void* const* d_in, const int* in_sizes, int n_in,
                              void* d_out, int out_size, void* d_ws, size_t ws_size,
                              hipStream_t stream)
{
    const int*   seq   = (const int*)  d_in[0];
    const float* embed = (const float*)d_in[1];
    const float* W1    = (const float*)d_in[2];
    const float* b1    = (const float*)d_in[3];
    const float* W2    = (const float*)d_in[4];
    const float* b2    = (const float*)d_in[5];
    const float* ln_g  = (const float*)d_in[6];
    const float* ln_b  = (const float*)d_in[7];
    const float* Ws    = (const float*)d_in[8];
    const float* bs    = (const float*)d_in[9];
    const float* We    = (const float*)d_in[10];
    const float* be    = (const float*)d_in[11];
    const float* Wo    = (const float*)d_in[12];
    const float* bo    = (const float*)d_in[13];
    float* out = (float*)d_out;

    float* Ktab = (float*)d_ws;                 // 2*64*32
    float* rden = Ktab + 2*VOC*HALF;            // 2*64
    float* Gtab = rden + 2*VOC;                 // 2*64*64
    float* ctx  = Gtab + 2*VOC*VOC;             // 128*64

    build_table_kernel<<<VOC, 64, 0, stream>>>(embed, W1, b1, W2, b2, ln_g, ln_b,
                                               Ws, bs, We, be, Ktab, rden);
    gram_kernel<<<2, 64, 0, stream>>>(Ktab, Gtab);
    chunk_scan_kernel<<<BATCH*2, 256, 0, stream>>>(seq, Ktab, rden, Gtab, ctx);
    out_kernel<<<BATCH, 64, 0, stream>>>(ctx, Wo, bo, out);
}

// Round 8
// 106.999 us; speedup vs baseline: 4.0879x; 1.2374x over previous
//
#include <hip/hip_runtime.h>

#define HD      64
#define VOC     64
#define HALF    32
#define BATCH   128
#define SEQLEN  2048

// ---------------------------------------------------------------------------
// Kernel 1: per-vocab table (unchanged; verified R1-R7).
// ---------------------------------------------------------------------------
__global__ __launch_bounds__(64) void build_table_kernel(
    const float* __restrict__ embed, const float* __restrict__ W1, const float* __restrict__ b1,
    const float* __restrict__ W2,    const float* __restrict__ b2,
    const float* __restrict__ ln_g,  const float* __restrict__ ln_b,
    const float* __restrict__ Ws,    const float* __restrict__ bs,
    const float* __restrict__ We,    const float* __restrict__ be,
    float* __restrict__ Ktab, float* __restrict__ rden)
{
    const int v = blockIdx.x;
    const int j = threadIdx.x;

    __shared__ float e_s[64];
    __shared__ float u_s[128];
    __shared__ float h_s[64];

    float e = embed[v*HD + j];
    e_s[j] = e;
    __syncthreads();

    float u0 = b1[j], u1 = b1[j + 64];
    #pragma unroll
    for (int i = 0; i < 64; ++i) {
        float ei = e_s[i];
        u0 = fmaf(ei, W1[i*128 + j],      u0);
        u1 = fmaf(ei, W1[i*128 + 64 + j], u1);
    }
    u_s[j]      = fmaxf(u0, 0.f);
    u_s[j + 64] = fmaxf(u1, 0.f);
    __syncthreads();

    float ff = b2[j];
    #pragma unroll
    for (int c = 0; c < 128; ++c) ff = fmaf(u_s[c], W2[c*64 + j], ff);

    float x = e + ff;
    float mu = x;
    #pragma unroll
    for (int m = 32; m; m >>= 1) mu += __shfl_xor(mu, m, 64);
    mu *= (1.f / 64.f);
    float d = x - mu;
    float var = d * d;
    #pragma unroll
    for (int m = 32; m; m >>= 1) var += __shfl_xor(var, m, 64);
    var *= (1.f / 64.f);
    float h = d * rsqrtf(var + 1e-5f) * ln_g[j] + ln_b[j];
    h_s[j] = h;
    __syncthreads();

    const int mm = j >> 5;
    const int jj = j & 31;
    const float* W  = mm ? We : Ws;
    float acc = mm ? be[jj] : bs[jj];
    #pragma unroll
    for (int i = 0; i < 64; ++i) acc = fmaf(h_s[i], W[i*32 + jj], acc);
    Ktab[(mm*VOC + v)*HALF + jj] = acc;

    float s = acc * acc;
    #pragma unroll
    for (int m = 16; m; m >>= 1) s += __shfl_xor(s, m, 32);
    if (jj == 0) rden[mm*VOC + v] = 1.f / (s + 1e-6f);
}

// ---------------------------------------------------------------------------
// Kernel 1b: gram table G[mm][v1][v2] = k_{v1} . k_{v2}. 2 blocks x 256 thr,
// float4 throughout (old 1-wave scalar version was ~10 us).
// ---------------------------------------------------------------------------
__global__ __launch_bounds__(256) void gram_kernel(
    const float* __restrict__ Ktab, float* __restrict__ Gtab)
{
    const int mm  = blockIdx.x;
    const int tid = threadIdx.x;
    const int v2  = tid & 63;
    const int qq  = tid >> 6;

    __shared__ __align__(16) float kt[VOC * HALF];
    {
        float4* d = (float4*)kt;
        const float4* s = (const float4*)(Ktab + mm*VOC*HALF);
        d[tid] = s[tid];
        d[tid + 256] = s[tid + 256];
    }
    __syncthreads();

    float4 r[8];
    #pragma unroll
    for (int j = 0; j < 8; ++j) r[j] = *(const float4*)&kt[v2*32 + 4*j];

    for (int v1 = qq*16; v1 < qq*16 + 16; ++v1) {
        float s0 = 0.f, s1 = 0.f, s2 = 0.f, s3 = 0.f;
        #pragma unroll
        for (int j = 0; j < 8; ++j) {
            float4 a = *(const float4*)&kt[v1*32 + 4*j];
            s0 = fmaf(a.x, r[j].x, s0);
            s1 = fmaf(a.y, r[j].y, s1);
            s2 = fmaf(a.z, r[j].z, s2);
            s3 = fmaf(a.w, r[j].w, s3);
        }
        Gtab[(mm*VOC + v1)*VOC + v2] = (s0 + s1) + (s2 + s3);
    }
}

// ---------------------------------------------------------------------------
// Kernel 2: chunked backward scan. One block per (batch, matrix) pair.
//
// Math (verified R7): ctx = sum_t w_t d_t k_t with d = (I+R)^-1 K z per chunk.
// NEW: per-chunk scaled column matrix Rcs[s][t] = (t<s) ? c_s*G[v_t,v_s] : 0,
// stride 36 (16B-aligned columns). Solve step s reads column s with <=4
// ds_read_b128 broadcasts; zeroed upper triangle makes the t<s mask free
// (fma by 0 is identity), and c_s is folded at build time.
// ---------------------------------------------------------------------------
__global__ __launch_bounds__(256) void chunk_scan_kernel(
    const int*   __restrict__ seq,
    const float* __restrict__ Ktab,
    const float* __restrict__ rden,
    const float* __restrict__ Gtab,
    float*       __restrict__ ctxg)
{
    const int bm   = blockIdx.x;      // 0..255
    const int b    = bm >> 1;
    const int mm   = bm & 1;
    const int tid  = threadIdx.x;
    const int lane = tid & 63;
    const int wave = tid >> 6;
    const int col  = lane & 31;       // 0..31
    const int half = lane >> 5;       // 0..1 (row half)

    __shared__ __align__(16) float ktp[VOC * 33];   // padded kt
    __shared__ __align__(16) float Gp [VOC * 65];   // padded gram
    __shared__ float rd_s[VOC];
    __shared__ int   sq[SEQLEN];
    __shared__ __align__(16) float Wl [4][32 * 36]; // chunk W, stride 36
    __shared__ __align__(16) float Rcs[4][32 * 36]; // scaled columns, stride 36
    __shared__ float carr[4][32], warr[4][32];
    __shared__ __align__(16) float z_l[32];
    __shared__ float a_l[32], b_l[32], ctx_l[32];

    // ---- stage tables ----
    for (int idx = tid; idx < VOC*HALF; idx += 256) {
        int v = idx >> 5, c = idx & 31;
        ktp[v*33 + c] = Ktab[mm*VOC*HALF + idx];
    }
    for (int idx = tid; idx < VOC*VOC; idx += 256) {
        int v1 = idx >> 6, v2 = idx & 63;
        Gp[v1*65 + v2] = Gtab[mm*VOC*VOC + idx];
    }
    if (tid < VOC) rd_s[tid] = rden[mm*VOC + tid];
    {
        const int4* S = (const int4*)(seq + b*SEQLEN);
        int4* D = (int4*)sq;
        D[tid] = S[tid];
        D[tid + 256] = S[tid + 256];
    }
    __syncthreads();

    if (tid < 32) { z_l[tid] = ktp[sq[SEQLEN-1]*33 + tid]; ctx_l[tid] = 0.f; }
    __syncthreads();

    const float inv = 1.0f / (float)SEQLEN;

    for (int r = 0; r < 16; ++r) {
        const int base = 60 - 4*r;            // chunk-set, descending over rounds
        const int T0   = (base + wave) << 5;  // this wave's chunk start key

        // per-chunk scalars c_t, w_t (pad key 2047 -> 0)
        if (lane < 32) {
            int tg = T0 + lane;
            int v  = sq[tg];
            float wgt = mm ? (float)(tg + 1) * inv : 1.0f;
            if (tg == SEQLEN-1) wgt = 0.f;
            carr[wave][lane] = rd_s[v] * wgt;
            warr[wave][lane] = wgt;
        }
        __builtin_amdgcn_sched_barrier(0);

        // init W rows: lane (col,half) owns rows half*16+i
        float w_[16]; int vo[16];
        #pragma unroll
        for (int i = 0; i < 16; ++i) {
            vo[i] = sq[T0 + half*16 + i];
            w_[i] = ktp[vo[i]*33 + col];
        }

        // build this wave's Rcs: lane (col,half) fills column s=col, rows 16h+i
        {
            const int vs = sq[T0 + col];
            const float cs = carr[wave][col];
            #pragma unroll
            for (int i = 0; i < 16; ++i) {
                float g   = Gp[vo[i]*65 + vs];
                float val = ((half*16 + i) < col) ? cs * g : 0.f;
                Rcs[wave][col*36 + half*16 + i] = val;
            }
        }
        __builtin_amdgcn_sched_barrier(0);

        // backward substitution: W_t -= sval * Rcs[s][t]  (upper rows no-op via 0)
        #pragma unroll
        for (int s = 31; s >= 1; --s) {
            const int so = s >> 4, sl = s & 15;
            float sent = w_[sl];
            float got  = __shfl_xor(sent, 32);
            float sval = (half == so) ? sent : got;       // W_s[col], broadcast
            const int nq = (s < 16) ? ((s + 3) >> 2) : 4;
            #pragma unroll
            for (int q = 0; q < nq; ++q) {
                float4 rc = *(const float4*)&Rcs[wave][s*36 + half*16 + (q<<2)];
                w_[4*q+0] = fmaf(-sval, rc.x, w_[4*q+0]);
                w_[4*q+1] = fmaf(-sval, rc.y, w_[4*q+1]);
                w_[4*q+2] = fmaf(-sval, rc.z, w_[4*q+2]);
                w_[4*q+3] = fmaf(-sval, rc.w, w_[4*q+3]);
            }
        }

        // publish W (stride 36; banks (4i+col)%32 -> conflict-free)
        #pragma unroll
        for (int i = 0; i < 16; ++i)
            Wl[wave][(half*16 + i)*36 + col] = w_[i];

        __syncthreads();

        // ---- sequential applies (wave 0), descending chunk order ----
        if (wave == 0) {
            for (int j = 3; j >= 0; --j) {
                const int T0j = (base + j) << 5;
                const int tl = col, h2 = half;
                // d_t = sum_col W[t][col] z[col]
                float pg = 0.f;
                #pragma unroll
                for (int q = 0; q < 4; ++q) {
                    float4 wr = *(const float4*)&Wl[j][tl*36 + h2*16 + 4*q];
                    float4 zv = *(const float4*)&z_l[h2*16 + 4*q];
                    pg = fmaf(wr.x, zv.x, pg);
                    pg = fmaf(wr.y, zv.y, pg);
                    pg = fmaf(wr.z, zv.z, pg);
                    pg = fmaf(wr.w, zv.w, pg);
                }
                float d  = pg + __shfl_xor(pg, 32);
                float al = carr[j][tl] * d;
                float bl = warr[j][tl] * d;
                if (h2 == 0) { a_l[tl] = al; b_l[tl] = bl; }
                __builtin_amdgcn_sched_barrier(0);
                // z[col] -= sum_t a_t k_t[col]; ctx[col] += sum_t b_t k_t[col]
                float pz = 0.f, pc = 0.f;
                #pragma unroll
                for (int i = 0; i < 16; ++i) {
                    int tg = T0j + h2*16 + i;
                    float kv = ktp[sq[tg]*33 + col];
                    pz = fmaf(a_l[h2*16 + i], kv, pz);
                    pc = fmaf(b_l[h2*16 + i], kv, pc);
                }
                float zo = __shfl_xor(pz, 32);
                float co = __shfl_xor(pc, 32);
                if (h2 == 0) {
                    z_l[col]   = z_l[col]   - (pz + zo);
                    ctx_l[col] = ctx_l[col] + (pc + co);
                }
                __builtin_amdgcn_sched_barrier(0);
            }
        }
        __syncthreads();
    }

    if (tid < 32) ctxg[b*64 + mm*32 + tid] = ctx_l[tid];
}

// ---------------------------------------------------------------------------
// Kernel 3: out = ctx @ Wo + bo.
// ---------------------------------------------------------------------------
__global__ __launch_bounds__(64) void out_kernel(
    const float* __restrict__ ctx, const float* __restrict__ Wo,
    const float* __restrict__ bo,  float* __restrict__ out)
{
    const int b = blockIdx.x;
    const int o = threadIdx.x;
    float acc = bo[o];
    #pragma unroll
    for (int i = 0; i < 64; ++i) acc = fmaf(ctx[b*64 + i], Wo[i*64 + o], acc);
    out[b*64 + o] = acc;
}

extern "C" void kernel_launch(void* const* d_in, const int* in_sizes, int n_in,
                              void* d_out, int out_size, void* d_ws, size_t ws_size,
                              hipStream_t stream)
{
    const int*   seq   = (const int*)  d_in[0];
    const float* embed = (const float*)d_in[1];
    const float* W1    = (const float*)d_in[2];
    const float* b1    = (const float*)d_in[3];
    const float* W2    = (const float*)d_in[4];
    const float* b2    = (const float*)d_in[5];
    const float* ln_g  = (const float*)d_in[6];
    const float* ln_b  = (const float*)d_in[7];
    const float* Ws    = (const float*)d_in[8];
    const float* bs    = (const float*)d_in[9];
    const float* We    = (const float*)d_in[10];
    const float* be    = (const float*)d_in[11];
    const float* Wo    = (const float*)d_in[12];
    const float* bo    = (const float*)d_in[13];
    float* out = (float*)d_out;

    float* Ktab = (float*)d_ws;                 // 2*64*32
    float* rden = Ktab + 2*VOC*HALF;            // 2*64
    float* Gtab = rden + 2*VOC;                 // 2*64*64
    float* ctx  = Gtab + 2*VOC*VOC;             // 128*64

    build_table_kernel<<<VOC, 64, 0, stream>>>(embed, W1, b1, W2, b2, ln_g, ln_b,
                                               Ws, bs, We, be, Ktab, rden);
    gram_kernel<<<2, 256, 0, stream>>>(Ktab, Gtab);
    chunk_scan_kernel<<<BATCH*2, 256, 0, stream>>>(seq, Ktab, rden, Gtab, ctx);
    out_kernel<<<BATCH, 64, 0, stream>>>(ctx, Wo, bo, out);
}

// Round 12
// 104.073 us; speedup vs baseline: 4.2028x; 1.0281x over previous
//
#include <hip/hip_runtime.h>

#define HD      64
#define VOC     64
#define HALF    32
#define BATCH   128
#define SEQLEN  2048

// ---------------------------------------------------------------------------
// Kernel 1: per-vocab table (unchanged; verified R1-R8).
// ---------------------------------------------------------------------------
__global__ __launch_bounds__(64) void build_table_kernel(
    const float* __restrict__ embed, const float* __restrict__ W1, const float* __restrict__ b1,
    const float* __restrict__ W2,    const float* __restrict__ b2,
    const float* __restrict__ ln_g,  const float* __restrict__ ln_b,
    const float* __restrict__ Ws,    const float* __restrict__ bs,
    const float* __restrict__ We,    const float* __restrict__ be,
    float* __restrict__ Ktab, float* __restrict__ rden)
{
    const int v = blockIdx.x;
    const int j = threadIdx.x;

    __shared__ float e_s[64];
    __shared__ float u_s[128];
    __shared__ float h_s[64];

    float e = embed[v*HD + j];
    e_s[j] = e;
    __syncthreads();

    float u0 = b1[j], u1 = b1[j + 64];
    #pragma unroll
    for (int i = 0; i < 64; ++i) {
        float ei = e_s[i];
        u0 = fmaf(ei, W1[i*128 + j],      u0);
        u1 = fmaf(ei, W1[i*128 + 64 + j], u1);
    }
    u_s[j]      = fmaxf(u0, 0.f);
    u_s[j + 64] = fmaxf(u1, 0.f);
    __syncthreads();

    float ff = b2[j];
    #pragma unroll
    for (int c = 0; c < 128; ++c) ff = fmaf(u_s[c], W2[c*64 + j], ff);

    float x = e + ff;
    float mu = x;
    #pragma unroll
    for (int m = 32; m; m >>= 1) mu += __shfl_xor(mu, m, 64);
    mu *= (1.f / 64.f);
    float d = x - mu;
    float var = d * d;
    #pragma unroll
    for (int m = 32; m; m >>= 1) var += __shfl_xor(var, m, 64);
    var *= (1.f / 64.f);
    float h = d * rsqrtf(var + 1e-5f) * ln_g[j] + ln_b[j];
    h_s[j] = h;
    __syncthreads();

    const int mm = j >> 5;
    const int jj = j & 31;
    const float* W  = mm ? We : Ws;
    float acc = mm ? be[jj] : bs[jj];
    #pragma unroll
    for (int i = 0; i < 64; ++i) acc = fmaf(h_s[i], W[i*32 + jj], acc);
    Ktab[(mm*VOC + v)*HALF + jj] = acc;

    float s = acc * acc;
    #pragma unroll
    for (int m = 16; m; m >>= 1) s += __shfl_xor(s, m, 32);
    if (jj == 0) rden[mm*VOC + v] = 1.f / (s + 1e-6f);
}

// ---------------------------------------------------------------------------
// Kernel 1b: gram table G[mm][v1][v2] = k_{v1} . k_{v2}. (unchanged R8)
// ---------------------------------------------------------------------------
__global__ __launch_bounds__(256) void gram_kernel(
    const float* __restrict__ Ktab, float* __restrict__ Gtab)
{
    const int mm  = blockIdx.x;
    const int tid = threadIdx.x;
    const int v2  = tid & 63;
    const int qq  = tid >> 6;

    __shared__ __align__(16) float kt[VOC * HALF];
    {
        float4* d = (float4*)kt;
        const float4* s = (const float4*)(Ktab + mm*VOC*HALF);
        d[tid] = s[tid];
        d[tid + 256] = s[tid + 256];
    }
    __syncthreads();

    float4 r[8];
    #pragma unroll
    for (int j = 0; j < 8; ++j) r[j] = *(const float4*)&kt[v2*32 + 4*j];

    for (int v1 = qq*16; v1 < qq*16 + 16; ++v1) {
        float s0 = 0.f, s1 = 0.f, s2 = 0.f, s3 = 0.f;
        #pragma unroll
        for (int j = 0; j < 8; ++j) {
            float4 a = *(const float4*)&kt[v1*32 + 4*j];
            s0 = fmaf(a.x, r[j].x, s0);
            s1 = fmaf(a.y, r[j].y, s1);
            s2 = fmaf(a.z, r[j].z, s2);
            s3 = fmaf(a.w, r[j].w, s3);
        }
        Gtab[(mm*VOC + v1)*VOC + v2] = (s0 + s1) + (s2 + s3);
    }
}

// ---------------------------------------------------------------------------
// Kernel 2: chunked backward scan. VERBATIM R8 (passed, 96us) infrastructure:
// scalar Rcs build, sched_barriers, inline kv loads, __shfl_xor apply.
// ONE change: COLUMN-PER-LANE solve — lane c holds all 32 rows of column c of
// W in registers; step s uses w_[s] in-register (no cross-lane op on the
// 31-step chain); Rcs read as wave-uniform float4 broadcasts (off-chain).
// Arithmetic op-for-op identical to R8's row solve.
// ---------------------------------------------------------------------------
__global__ __launch_bounds__(256) void chunk_scan_kernel(
    const int*   __restrict__ seq,
    const float* __restrict__ Ktab,
    const float* __restrict__ rden,
    const float* __restrict__ Gtab,
    float*       __restrict__ ctxg)
{
    const int bm   = blockIdx.x;      // 0..255
    const int b    = bm >> 1;
    const int mm   = bm & 1;
    const int tid  = threadIdx.x;
    const int lane = tid & 63;
    const int wave = tid >> 6;
    const int col  = lane & 31;       // 0..31
    const int half = lane >> 5;       // 0..1 (row half)

    __shared__ __align__(16) float ktp[VOC * 33];   // padded kt
    __shared__ __align__(16) float Gp [VOC * 65];   // padded gram
    __shared__ float rd_s[VOC];
    __shared__ int   sq[SEQLEN];
    __shared__ __align__(16) float Wl [4][32 * 36]; // chunk W, stride 36
    __shared__ __align__(16) float Rcs[4][32 * 36]; // scaled columns, stride 36
    __shared__ float carr[4][32], warr[4][32];
    __shared__ __align__(16) float z_l[32];
    __shared__ float a_l[32], b_l[32], ctx_l[32];

    // ---- stage tables ----
    for (int idx = tid; idx < VOC*HALF; idx += 256) {
        int v = idx >> 5, c = idx & 31;
        ktp[v*33 + c] = Ktab[mm*VOC*HALF + idx];
    }
    for (int idx = tid; idx < VOC*VOC; idx += 256) {
        int v1 = idx >> 6, v2 = idx & 63;
        Gp[v1*65 + v2] = Gtab[mm*VOC*VOC + idx];
    }
    if (tid < VOC) rd_s[tid] = rden[mm*VOC + tid];
    {
        const int4* S = (const int4*)(seq + b*SEQLEN);
        int4* D = (int4*)sq;
        D[tid] = S[tid];
        D[tid + 256] = S[tid + 256];
    }
    __syncthreads();

    if (tid < 32) { z_l[tid] = ktp[sq[SEQLEN-1]*33 + tid]; ctx_l[tid] = 0.f; }
    __syncthreads();

    const float inv = 1.0f / (float)SEQLEN;

    for (int r = 0; r < 16; ++r) {
        const int base = 60 - 4*r;            // chunk-set, descending over rounds
        const int T0   = (base + wave) << 5;  // this wave's chunk start key

        // per-chunk scalars c_t, w_t (pad key 2047 -> 0)   [verbatim R8]
        if (lane < 32) {
            int tg = T0 + lane;
            int v  = sq[tg];
            float wgt = mm ? (float)(tg + 1) * inv : 1.0f;
            if (tg == SEQLEN-1) wgt = 0.f;
            carr[wave][lane] = rd_s[v] * wgt;
            warr[wave][lane] = wgt;
        }
        __builtin_amdgcn_sched_barrier(0);

        // ids for this half's rows (feeds the Rcs build)   [verbatim R8]
        int vo[16];
        #pragma unroll
        for (int i = 0; i < 16; ++i)
            vo[i] = sq[T0 + half*16 + i];

        // build this wave's Rcs: lane (col,half) fills column s=col, rows 16h+i
        // [verbatim R8: scalar writes]
        {
            const int vs = sq[T0 + col];
            const float cs = carr[wave][col];
            #pragma unroll
            for (int i = 0; i < 16; ++i) {
                float g   = Gp[vo[i]*65 + vs];
                float val = ((half*16 + i) < col) ? cs * g : 0.f;
                Rcs[wave][col*36 + half*16 + i] = val;
            }
        }
        __builtin_amdgcn_sched_barrier(0);

        // ---- COLUMN-PER-LANE solve (the one change vs R8) ----
        // init W column col: w_[t] = k_{v_t}[col]; lanes 32-63 mirror lanes 0-31.
        float w_[32];
        #pragma unroll
        for (int t = 0; t < 32; ++t)
            w_[t] = ktp[sq[T0 + t]*33 + col];

        // backward substitution: w_[t] -= Rcs[s][t] * w_[s] for t<s
        // (entries t>=s are zero by construction -> extra quad lanes are no-ops)
        #pragma unroll
        for (int s = 31; s >= 1; --s) {
            const float ws = w_[s];
            const int nq = (s + 3) >> 2;          // ceil(s/4) quads cover t<s
            #pragma unroll
            for (int q = 0; q < nq; ++q) {
                float4 rc = *(const float4*)&Rcs[wave][s*36 + 4*q];
                w_[4*q+0] = fmaf(-ws, rc.x, w_[4*q+0]);
                w_[4*q+1] = fmaf(-ws, rc.y, w_[4*q+1]);
                w_[4*q+2] = fmaf(-ws, rc.z, w_[4*q+2]);
                w_[4*q+3] = fmaf(-ws, rc.w, w_[4*q+3]);
            }
        }

        // publish W rows (lanes 0-31; lanes 32-63 hold identical mirrors)
        if (lane < 32) {
            #pragma unroll
            for (int t = 0; t < 32; ++t)
                Wl[wave][t*36 + col] = w_[t];
        }

        __syncthreads();

        // ---- sequential applies (wave 0), descending chunk order [verbatim R8]
        if (wave == 0) {
            #pragma unroll
            for (int j = 3; j >= 0; --j) {
                const int T0j = (base + j) << 5;
                const int tl = col, h2 = half;
                // d_t = sum_col W[t][col] z[col]
                float pg = 0.f;
                #pragma unroll
                for (int q = 0; q < 4; ++q) {
                    float4 wr = *(const float4*)&Wl[j][tl*36 + h2*16 + 4*q];
                    float4 zv = *(const float4*)&z_l[h2*16 + 4*q];
                    pg = fmaf(wr.x, zv.x, pg);
                    pg = fmaf(wr.y, zv.y, pg);
                    pg = fmaf(wr.z, zv.z, pg);
                    pg = fmaf(wr.w, zv.w, pg);
                }
                float d  = pg + __shfl_xor(pg, 32);
                float al = carr[j][tl] * d;
                float bl = warr[j][tl] * d;
                if (h2 == 0) { a_l[tl] = al; b_l[tl] = bl; }
                __builtin_amdgcn_sched_barrier(0);
                // z[col] -= sum_t a_t k_t[col]; ctx[col] += sum_t b_t k_t[col]
                float pz = 0.f, pc = 0.f;
                #pragma unroll
                for (int i = 0; i < 16; ++i) {
                    int tg = T0j + h2*16 + i;
                    float kv = ktp[sq[tg]*33 + col];
                    pz = fmaf(a_l[h2*16 + i], kv, pz);
                    pc = fmaf(b_l[h2*16 + i], kv, pc);
                }
                float zo = __shfl_xor(pz, 32);
                float co = __shfl_xor(pc, 32);
                if (h2 == 0) {
                    z_l[col]   = z_l[col]   - (pz + zo);
                    ctx_l[col] = ctx_l[col] + (pc + co);
                }
                __builtin_amdgcn_sched_barrier(0);
            }
        }
        __syncthreads();
    }

    if (tid < 32) ctxg[b*64 + mm*32 + tid] = ctx_l[tid];
}

// ---------------------------------------------------------------------------
// Kernel 3: out = ctx @ Wo + bo.
// ---------------------------------------------------------------------------
__global__ __launch_bounds__(64) void out_kernel(
    const float* __restrict__ ctx, const float* __restrict__ Wo,
    const float* __restrict__ bo,  float* __restrict__ out)
{
    const int b = blockIdx.x;
    const int o = threadIdx.x;
    float acc = bo[o];
    #pragma unroll
    for (int i = 0; i < 64; ++i) acc = fmaf(ctx[b*64 + i], Wo[i*64 + o], acc);
    out[b*64 + o] = acc;
}

extern "C" void kernel_launch(void* const* d_in, const int* in_sizes, int n_in,
                              void* d_out, int out_size, void* d_ws, size_t ws_size,
                              hipStream_t stream)
{
    const int*   seq   = (const int*)  d_in[0];
    const float* embed = (const float*)d_in[1];
    const float* W1    = (const float*)d_in[2];
    const float* b1    = (const float*)d_in[3];
    const float* W2    = (const float*)d_in[4];
    const float* b2    = (const float*)d_in[5];
    const float* ln_g  = (const float*)d_in[6];
    const float* ln_b  = (const float*)d_in[7];
    const float* Ws    = (const float*)d_in[8];
    const float* bs    = (const float*)d_in[9];
    const float* We    = (const float*)d_in[10];
    const float* be    = (const float*)d_in[11];
    const float* Wo    = (const float*)d_in[12];
    const float* bo    = (const float*)d_in[13];
    float* out = (float*)d_out;

    float* Ktab = (float*)d_ws;                 // 2*64*32
    float* rden = Ktab + 2*VOC*HALF;            // 2*64
    float* Gtab = rden + 2*VOC;                 // 2*64*64
    float* ctx  = Gtab + 2*VOC*VOC;             // 128*64

    build_table_kernel<<<VOC, 64, 0, stream>>>(embed, W1, b1, W2, b2, ln_g, ln_b,
                                               Ws, bs, We, be, Ktab, rden);
    gram_kernel<<<2, 256, 0, stream>>>(Ktab, Gtab);
    chunk_scan_kernel<<<BATCH*2, 256, 0, stream>>>(seq, Ktab, rden, Gtab, ctx);
    out_kernel<<<BATCH, 64, 0, stream>>>(ctx, Wo, bo, out);
}

// Round 13
// 84.671 us; speedup vs baseline: 5.1659x; 1.2291x over previous
//
#include <hip/hip_runtime.h>

#define HD      64
#define VOC     64
#define HALF    32
#define BATCH   128
#define SEQLEN  2048

// ---------------------------------------------------------------------------
// Kernel 1: per-vocab table (unchanged; verified R1-R12).
// ---------------------------------------------------------------------------
__global__ __launch_bounds__(64) void build_table_kernel(
    const float* __restrict__ embed, const float* __restrict__ W1, const float* __restrict__ b1,
    const float* __restrict__ W2,    const float* __restrict__ b2,
    const float* __restrict__ ln_g,  const float* __restrict__ ln_b,
    const float* __restrict__ Ws,    const float* __restrict__ bs,
    const float* __restrict__ We,    const float* __restrict__ be,
    float* __restrict__ Ktab, float* __restrict__ rden)
{
    const int v = blockIdx.x;
    const int j = threadIdx.x;

    __shared__ float e_s[64];
    __shared__ float u_s[128];
    __shared__ float h_s[64];

    float e = embed[v*HD + j];
    e_s[j] = e;
    __syncthreads();

    float u0 = b1[j], u1 = b1[j + 64];
    #pragma unroll
    for (int i = 0; i < 64; ++i) {
        float ei = e_s[i];
        u0 = fmaf(ei, W1[i*128 + j],      u0);
        u1 = fmaf(ei, W1[i*128 + 64 + j], u1);
    }
    u_s[j]      = fmaxf(u0, 0.f);
    u_s[j + 64] = fmaxf(u1, 0.f);
    __syncthreads();

    float ff = b2[j];
    #pragma unroll
    for (int c = 0; c < 128; ++c) ff = fmaf(u_s[c], W2[c*64 + j], ff);

    float x = e + ff;
    float mu = x;
    #pragma unroll
    for (int m = 32; m; m >>= 1) mu += __shfl_xor(mu, m, 64);
    mu *= (1.f / 64.f);
    float d = x - mu;
    float var = d * d;
    #pragma unroll
    for (int m = 32; m; m >>= 1) var += __shfl_xor(var, m, 64);
    var *= (1.f / 64.f);
    float h = d * rsqrtf(var + 1e-5f) * ln_g[j] + ln_b[j];
    h_s[j] = h;
    __syncthreads();

    const int mm = j >> 5;
    const int jj = j & 31;
    const float* W  = mm ? We : Ws;
    float acc = mm ? be[jj] : bs[jj];
    #pragma unroll
    for (int i = 0; i < 64; ++i) acc = fmaf(h_s[i], W[i*32 + jj], acc);
    Ktab[(mm*VOC + v)*HALF + jj] = acc;

    float s = acc * acc;
    #pragma unroll
    for (int m = 16; m; m >>= 1) s += __shfl_xor(s, m, 32);
    if (jj == 0) rden[mm*VOC + v] = 1.f / (s + 1e-6f);
}

// ---------------------------------------------------------------------------
// Kernel 1b: gram table G[mm][v1][v2] = k_{v1} . k_{v2}. (unchanged R8)
// ---------------------------------------------------------------------------
__global__ __launch_bounds__(256) void gram_kernel(
    const float* __restrict__ Ktab, float* __restrict__ Gtab)
{
    const int mm  = blockIdx.x;
    const int tid = threadIdx.x;
    const int v2  = tid & 63;
    const int qq  = tid >> 6;

    __shared__ __align__(16) float kt[VOC * HALF];
    {
        float4* d = (float4*)kt;
        const float4* s = (const float4*)(Ktab + mm*VOC*HALF);
        d[tid] = s[tid];
        d[tid + 256] = s[tid + 256];
    }
    __syncthreads();

    float4 r[8];
    #pragma unroll
    for (int j = 0; j < 8; ++j) r[j] = *(const float4*)&kt[v2*32 + 4*j];

    for (int v1 = qq*16; v1 < qq*16 + 16; ++v1) {
        float s0 = 0.f, s1 = 0.f, s2 = 0.f, s3 = 0.f;
        #pragma unroll
        for (int j = 0; j < 8; ++j) {
            float4 a = *(const float4*)&kt[v1*32 + 4*j];
            s0 = fmaf(a.x, r[j].x, s0);
            s1 = fmaf(a.y, r[j].y, s1);
            s2 = fmaf(a.z, r[j].z, s2);
            s3 = fmaf(a.w, r[j].w, s3);
        }
        Gtab[(mm*VOC + v1)*VOC + v2] = (s0 + s1) + (s2 + s3);
    }
}

// ---------------------------------------------------------------------------
// Kernel 2: chunked backward scan, SOFTWARE-PIPELINED rounds.
// Chunk-sets of 3. Per round r: wave 0 applies set r (double-buffered W/Kd/
// carr/warr, parity r&1) while waves 1-3 solve set r+1 (parity (r+1)&1).
// Solve code is VERBATIM R12 (passed): scalar Rcs writes, sched_barriers,
// column-per-lane substitution. Apply: full-row b128 reads (no shfl on the
// chain), Kd = chunk K matrix published by the solver, ctx in registers.
// ---------------------------------------------------------------------------
__global__ __launch_bounds__(256) void chunk_scan_kernel(
    const int*   __restrict__ seq,
    const float* __restrict__ Ktab,
    const float* __restrict__ rden,
    const float* __restrict__ Gtab,
    float*       __restrict__ ctxg)
{
    const int bm   = blockIdx.x;      // 0..255
    const int b    = bm >> 1;
    const int mm   = bm & 1;
    const int tid  = threadIdx.x;
    const int lane = tid & 63;
    const int wave = tid >> 6;
    const int col  = lane & 31;       // 0..31
    const int half = lane >> 5;       // 0..1

    __shared__ __align__(16) float ktp[VOC * 33];      // padded kt
    __shared__ __align__(16) float Gp [VOC * 65];      // padded gram
    __shared__ float rd_s[VOC];
    __shared__ int   sq[SEQLEN];
    __shared__ __align__(16) float Wl [2][3][32 * 36]; // W rows, double-buffered
    __shared__ __align__(16) float Kd [2][3][32 * 36]; // Kd[c*36+t] = k_{v_t}[c]
    __shared__ __align__(16) float Rcs[3][32 * 36];    // solver-local scratch
    __shared__ float carr[2][3][32], warr[2][3][32];
    __shared__ __align__(16) float z_l[32];
    __shared__ float a_l[32], b_l[32];

    // ---- stage tables (verbatim R12) ----
    for (int idx = tid; idx < VOC*HALF; idx += 256) {
        int v = idx >> 5, c = idx & 31;
        ktp[v*33 + c] = Ktab[mm*VOC*HALF + idx];
    }
    for (int idx = tid; idx < VOC*VOC; idx += 256) {
        int v1 = idx >> 6, v2 = idx & 63;
        Gp[v1*65 + v2] = Gtab[mm*VOC*VOC + idx];
    }
    if (tid < VOC) rd_s[tid] = rden[mm*VOC + tid];
    {
        const int4* S = (const int4*)(seq + b*SEQLEN);
        int4* D = (int4*)sq;
        D[tid] = S[tid];
        D[tid + 256] = S[tid + 256];
    }
    __syncthreads();

    if (tid < 32) z_l[tid] = ktp[sq[SEQLEN-1]*33 + tid];
    __syncthreads();

    const float inv = 1.0f / (float)SEQLEN;

    // ---- solver: chunk ck into buffer p, slot (verbatim R12 arithmetic) ----
    auto SOLVE = [&](int ck, int p, int slot) {
        const int T0 = ck << 5;
        if (lane < 32) {
            int tg = T0 + lane;
            int v  = sq[tg];
            float wgt = mm ? (float)(tg + 1) * inv : 1.0f;
            if (tg == SEQLEN-1) wgt = 0.f;
            carr[p][slot][lane] = rd_s[v] * wgt;
            warr[p][slot][lane] = wgt;
        }
        __builtin_amdgcn_sched_barrier(0);

        int vo[16];
        #pragma unroll
        for (int i = 0; i < 16; ++i)
            vo[i] = sq[T0 + half*16 + i];

        // Rcs build: scalar writes (verbatim R12 — do NOT change to b128)
        {
            const int vs = sq[T0 + col];
            const float cs = carr[p][slot][col];
            #pragma unroll
            for (int i = 0; i < 16; ++i) {
                float g   = Gp[vo[i]*65 + vs];
                float val = ((half*16 + i) < col) ? cs * g : 0.f;
                Rcs[slot][col*36 + half*16 + i] = val;
            }
        }
        __builtin_amdgcn_sched_barrier(0);

        // column-per-lane init; publish Kd rows BEFORE substitution mutates w_
        float w_[32];
        #pragma unroll
        for (int t = 0; t < 32; ++t)
            w_[t] = ktp[sq[T0 + t]*33 + col];
        if (lane < 32) {
            #pragma unroll
            for (int q = 0; q < 8; ++q) {
                float4 f;
                f.x = w_[4*q+0]; f.y = w_[4*q+1];
                f.z = w_[4*q+2]; f.w = w_[4*q+3];
                *(float4*)&Kd[p][slot][col*36 + 4*q] = f;
            }
        }

        // backward substitution (verbatim R12)
        #pragma unroll
        for (int s = 31; s >= 1; --s) {
            const float ws = w_[s];
            const int nq = (s + 3) >> 2;
            #pragma unroll
            for (int q = 0; q < nq; ++q) {
                float4 rc = *(const float4*)&Rcs[slot][s*36 + 4*q];
                w_[4*q+0] = fmaf(-ws, rc.x, w_[4*q+0]);
                w_[4*q+1] = fmaf(-ws, rc.y, w_[4*q+1]);
                w_[4*q+2] = fmaf(-ws, rc.z, w_[4*q+2]);
                w_[4*q+3] = fmaf(-ws, rc.w, w_[4*q+3]);
            }
        }

        if (lane < 32) {
            #pragma unroll
            for (int t = 0; t < 32; ++t)
                Wl[p][slot][t*36 + col] = w_[t];
        }
    };

    float ctx_r = 0.f;

    // ---- applier: chunk in buffer p, slot; same sums as R12, full-row reads ----
    auto APPLY = [&](int p, int slot) {
        // d_t = sum_c W[t][c] z[c]   (lane t = col; lanes 32-63 duplicate)
        float pg0 = 0.f, pg1 = 0.f, pg2 = 0.f, pg3 = 0.f;
        const float* wrow = &Wl[p][slot][col*36];
        #pragma unroll
        for (int q = 0; q < 8; ++q) {
            float4 wr = *(const float4*)&wrow[4*q];
            float4 zv = *(const float4*)&z_l[4*q];
            pg0 = fmaf(wr.x, zv.x, pg0);
            pg1 = fmaf(wr.y, zv.y, pg1);
            pg2 = fmaf(wr.z, zv.z, pg2);
            pg3 = fmaf(wr.w, zv.w, pg3);
        }
        float d  = (pg0 + pg1) + (pg2 + pg3);
        float al = carr[p][slot][col] * d;
        float bl = warr[p][slot][col] * d;
        if (lane < 32) { a_l[col] = al; b_l[col] = bl; }
        __builtin_amdgcn_sched_barrier(0);

        // z[c] -= sum_t a_t Kd[c][t];  ctx[c] += sum_t b_t Kd[c][t]
        float pz0 = 0.f, pz1 = 0.f, pc0 = 0.f, pc1 = 0.f;
        const float* krow = &Kd[p][slot][col*36];
        #pragma unroll
        for (int q = 0; q < 8; ++q) {
            float4 k4 = *(const float4*)&krow[4*q];
            float4 a4 = *(const float4*)&a_l[4*q];
            float4 b4 = *(const float4*)&b_l[4*q];
            pz0 = fmaf(a4.x, k4.x, pz0);
            pz1 = fmaf(a4.y, k4.y, pz1);
            pz0 = fmaf(a4.z, k4.z, pz0);
            pz1 = fmaf(a4.w, k4.w, pz1);
            pc0 = fmaf(b4.x, k4.x, pc0);
            pc1 = fmaf(b4.y, k4.y, pc1);
            pc0 = fmaf(b4.z, k4.z, pc0);
            pc1 = fmaf(b4.w, k4.w, pc1);
        }
        if (lane < 32) z_l[col] = z_l[col] - (pz0 + pz1);
        ctx_r += (pc0 + pc1);
        __builtin_amdgcn_sched_barrier(0);
    };

    // ---- prologue: solve set 0 (chunks 61,62,63) into buffer 0 ----
    if (wave > 0) SOLVE(61 + (wave - 1), 0, wave - 1);
    __syncthreads();

    // ---- pipelined rounds: apply set r (buf r&1) || solve set r+1 (buf ~r&1)
    for (int r = 0; r <= 21; ++r) {
        const int baseA = 61 - 3*r;
        if (wave == 0) {
            #pragma unroll
            for (int j = 2; j >= 0; --j) {
                if (baseA + j >= 0) APPLY(r & 1, j);
            }
        } else if (r < 21) {
            int ck = (61 - 3*(r+1)) + (wave - 1);
            if (ck >= 0) SOLVE(ck, (r+1) & 1, wave - 1);
        }
        __syncthreads();
    }

    if (tid < 32) ctxg[b*64 + mm*32 + tid] = ctx_r;
}

// ---------------------------------------------------------------------------
// Kernel 3: out = ctx @ Wo + bo.
// ---------------------------------------------------------------------------
__global__ __launch_bounds__(64) void out_kernel(
    const float* __restrict__ ctx, const float* __restrict__ Wo,
    const float* __restrict__ bo,  float* __restrict__ out)
{
    const int b = blockIdx.x;
    const int o = threadIdx.x;
    float acc = bo[o];
    #pragma unroll
    for (int i = 0; i < 64; ++i) acc = fmaf(ctx[b*64 + i], Wo[i*64 + o], acc);
    out[b*64 + o] = acc;
}

extern "C" void kernel_launch(void* const* d_in, const int* in_sizes, int n_in,
                              void* d_out, int out_size, void* d_ws, size_t ws_size,
                              hipStream_t stream)
{
    const int*   seq   = (const int*)  d_in[0];
    const float* embed = (const float*)d_in[1];
    const float* W1    = (const float*)d_in[2];
    const float* b1    = (const float*)d_in[3];
    const float* W2    = (const float*)d_in[4];
    const float* b2    = (const float*)d_in[5];
    const float* ln_g  = (const float*)d_in[6];
    const float* ln_b  = (const float*)d_in[7];
    const float* Ws    = (const float*)d_in[8];
    const float* bs    = (const float*)d_in[9];
    const float* We    = (const float*)d_in[10];
    const float* be    = (const float*)d_in[11];
    const float* Wo    = (const float*)d_in[12];
    const float* bo    = (const float*)d_in[13];
    float* out = (float*)d_out;

    float* Ktab = (float*)d_ws;                 // 2*64*32
    float* rden = Ktab + 2*VOC*HALF;            // 2*64
    float* Gtab = rden + 2*VOC;                 // 2*64*64
    float* ctx  = Gtab + 2*VOC*VOC;             // 128*64

    build_table_kernel<<<VOC, 64, 0, stream>>>(embed, W1, b1, W2, b2, ln_g, ln_b,
                                               Ws, bs, We, be, Ktab, rden);
    gram_kernel<<<2, 256, 0, stream>>>(Ktab, Gtab);
    chunk_scan_kernel<<<BATCH*2, 256, 0, stream>>>(seq, Ktab, rden, Gtab, ctx);
    out_kernel<<<BATCH, 64, 0, stream>>>(ctx, Wo, bo, out);
}